// Round 1
// baseline (353.516 us; speedup 1.0000x reference)
//
#include <hip/hip_runtime.h>
#include <hip/hip_bf16.h>

#define BB 16
#define NN 1024
#define CS 256
#define CX 64
#define CC 320
#define PH 64
#define GH 128
#define ELLW 64

typedef __hip_bfloat16 bf16;

// ---------------- zero the ELL row counters ----------------
__global__ __launch_bounds__(256) void k_zero_cnt(int* __restrict__ cnt) {
    int idx = blockIdx.x * 256 + threadIdx.x;
    if (idx < BB * NN) cnt[idx] = 0;
}

// ---------------- stage 1: h = |f_i - f_j| @ W1 + b1  -> bf16 [B,64,E] ----
__global__ __launch_bounds__(256) void k_edge_h(
    const float* __restrict__ search, const float* __restrict__ xcorr,
    const int* __restrict__ pairs, const float* __restrict__ w1,
    const float* __restrict__ b1, bf16* __restrict__ hstore, int E, int nb)
{
    int b = blockIdx.x / nb;
    int e = (blockIdx.x % nb) * 256 + threadIdx.x;
    bool valid = e < E;
    int ee = valid ? e : 0;
    const int* cp = pairs + (((size_t)b * E) + ee) * 2;
    int i = cp[0], j = cp[1];
    const float* sb = search + (size_t)b * CS * NN;
    const float* xb = xcorr + (size_t)b * CX * NN;

    float acc[PH];
    #pragma unroll
    for (int l = 0; l < PH; ++l) acc[l] = b1[l];

    #pragma unroll 1
    for (int c = 0; c < CS; ++c) {
        float fi = sb[c * NN + i];
        float fj = sb[c * NN + j];
        float d = fabsf(fi - fj);
        const float* wr = w1 + c * PH;     // wave-uniform -> SGPR loads
        #pragma unroll
        for (int l = 0; l < PH; ++l) acc[l] = fmaf(d, wr[l], acc[l]);
    }
    #pragma unroll 1
    for (int c = 0; c < CX; ++c) {
        float fi = xb[c * NN + i];
        float fj = xb[c * NN + j];
        float d = fabsf(fi - fj);
        const float* wr = w1 + (CS + c) * PH;
        #pragma unroll
        for (int l = 0; l < PH; ++l) acc[l] = fmaf(d, wr[l], acc[l]);
    }
    if (valid) {
        #pragma unroll
        for (int l = 0; l < PH; ++l)
            hstore[((size_t)b * PH + l) * E + e] = __float2bfloat16(acc[l]);
    }
}

// ---------------- stage 2: BN stats per (b, l) over E -----------------
__global__ __launch_bounds__(256) void k_bn_stats(
    const bf16* __restrict__ hstore, float* __restrict__ mu_a,
    float* __restrict__ rs_a, int E)
{
    int row = blockIdx.x;  // b*64 + l
    const bf16* hp = hstore + (size_t)row * E;
    float s = 0.f, s2 = 0.f;
    for (int e = threadIdx.x; e < E; e += 256) {
        float v = __bfloat162float(hp[e]);
        s += v; s2 += v * v;
    }
    #pragma unroll
    for (int off = 32; off >= 1; off >>= 1) {
        s  += __shfl_down(s,  off, 64);
        s2 += __shfl_down(s2, off, 64);
    }
    __shared__ float ls[4], ls2[4];
    int lane = threadIdx.x & 63, w = threadIdx.x >> 6;
    if (lane == 0) { ls[w] = s; ls2[w] = s2; }
    __syncthreads();
    if (threadIdx.x == 0) {
        float S  = ls[0] + ls[1] + ls[2] + ls[3];
        float S2 = ls2[0] + ls2[1] + ls2[2] + ls2[3];
        float mu = S / E;
        float var = S2 / E - mu * mu;
        mu_a[row] = mu;
        rs_a[row] = rsqrtf(var + 1e-5f);
    }
}

// -------- stage 3: edge value (BN+ReLU+Linear+sigmoid) + ELL scatter -----
__global__ __launch_bounds__(256) void k_edge_val(
    const bf16* __restrict__ hstore, const float* __restrict__ mu_a,
    const float* __restrict__ rs_a, const float* __restrict__ gamma,
    const float* __restrict__ beta, const float* __restrict__ w2,
    const float* __restrict__ b2, const int* __restrict__ pairs,
    int* __restrict__ cnt, int* __restrict__ ecol, float* __restrict__ eval_,
    int E, int nb)
{
    int b = blockIdx.x / nb;
    int e = (blockIdx.x % nb) * 256 + threadIdx.x;
    if (e >= E) return;
    float acc = 0.f;
    #pragma unroll
    for (int l = 0; l < PH; ++l) {
        float v = __bfloat162float(hstore[((size_t)b * PH + l) * E + e]);
        float x = (v - mu_a[b * PH + l]) * rs_a[b * PH + l] * gamma[l] + beta[l];
        x = x > 0.f ? x : 0.f;
        acc = fmaf(x, w2[l], acc);
    }
    float edge = 1.f / (1.f + __expf(-(acc + b2[0])));
    const int* cp = pairs + ((size_t)b * E + e) * 2;
    int i = cp[0], j = cp[1];
    int row = b * NN + i;
    int slot = atomicAdd(&cnt[row], 1);
    if (slot < ELLW) {
        ecol[row * ELLW + slot]  = j;
        eval_[row * ELLW + slot] = edge;
    }
}

// ---------------- stage 4: g1 = node_feat @ gc1_w  [B*N,320]@[320,128] ----
__global__ __launch_bounds__(256) void k_gc1(
    const float* __restrict__ search, const float* __restrict__ xcorr,
    const float* __restrict__ w, float* __restrict__ g1)
{
    int b = blockIdx.x >> 4;
    int ntile = (blockIdx.x & 15) * 64;
    __shared__ float As[32 * 64];
    __shared__ float Wsh[32 * 128];
    int tid = threadIdx.x;
    int d0 = (tid & 15) * 8;
    int n0 = (tid >> 4) * 4;
    float Creg[4][8];
    #pragma unroll
    for (int ii = 0; ii < 4; ++ii)
        #pragma unroll
        for (int jj = 0; jj < 8; ++jj) Creg[ii][jj] = 0.f;

    const float* sb = search + (size_t)b * CS * NN;
    const float* xb = xcorr + (size_t)b * CX * NN;

    for (int k0 = 0; k0 < CC; k0 += 32) {
        #pragma unroll
        for (int f = 0; f < 8; ++f) {
            int idx = tid + f * 256;
            int cc = idx >> 6, nn = idx & 63;
            int c = k0 + cc;
            As[idx] = (c < CS) ? sb[c * NN + ntile + nn]
                               : xb[(c - CS) * NN + ntile + nn];
        }
        #pragma unroll
        for (int f = 0; f < 16; ++f) {
            int idx = tid + f * 256;
            int cc = idx >> 7, dd = idx & 127;
            Wsh[idx] = w[(k0 + cc) * GH + dd];
        }
        __syncthreads();
        #pragma unroll 1
        for (int cc = 0; cc < 32; ++cc) {
            const float* ap = &As[cc * 64 + n0];
            float a0 = ap[0], a1 = ap[1], a2 = ap[2], a3 = ap[3];
            const float* wp = &Wsh[cc * 128 + d0];
            float wv[8];
            #pragma unroll
            for (int jj = 0; jj < 8; ++jj) wv[jj] = wp[jj];
            #pragma unroll
            for (int jj = 0; jj < 8; ++jj) {
                Creg[0][jj] = fmaf(a0, wv[jj], Creg[0][jj]);
                Creg[1][jj] = fmaf(a1, wv[jj], Creg[1][jj]);
                Creg[2][jj] = fmaf(a2, wv[jj], Creg[2][jj]);
                Creg[3][jj] = fmaf(a3, wv[jj], Creg[3][jj]);
            }
        }
        __syncthreads();
    }
    #pragma unroll
    for (int ii = 0; ii < 4; ++ii) {
        size_t o = ((size_t)b * NN + ntile + n0 + ii) * GH + d0;
        #pragma unroll
        for (int jj = 0; jj < 8; ++jj) g1[o + jj] = Creg[ii][jj];
    }
}

// ------- stage 5: h1 = leaky(adj @ g1); g2 = h1 @ gc2_w  (fused) ---------
__global__ __launch_bounds__(128) void k_spmm1(
    const float* __restrict__ g1, const int* __restrict__ cnt,
    const int* __restrict__ ecol, const float* __restrict__ eval_,
    const float* __restrict__ w2g, float* __restrict__ g2)
{
    __shared__ float tmp[2];
    int tid = threadIdx.x;
    float wv = w2g[tid];
    for (int nn = 0; nn < 8; ++nn) {
        int node = blockIdx.x * 8 + nn;
        int b = node >> 10;
        int c = cnt[node];
        float acc = 0.f;
        for (int s = 0; s < c; ++s) {
            int j   = ecol[node * ELLW + s];
            float v = eval_[node * ELLW + s];
            acc = fmaf(v, g1[((size_t)b * NN + j) * GH + tid], acc);
        }
        float h1 = acc > 0.f ? acc : 0.2f * acc;
        float p = h1 * wv;
        #pragma unroll
        for (int off = 32; off >= 1; off >>= 1) p += __shfl_down(p, off, 64);
        if ((tid & 63) == 0) tmp[tid >> 6] = p;
        __syncthreads();
        if (tid == 0) g2[node] = tmp[0] + tmp[1];
        __syncthreads();
    }
}

// ------------- stage 6: out = sigmoid(adj @ g2) --------------------------
__global__ __launch_bounds__(256) void k_spmm2(
    const float* __restrict__ g2, const int* __restrict__ cnt,
    const int* __restrict__ ecol, const float* __restrict__ eval_,
    float* __restrict__ out)
{
    int node = blockIdx.x * 256 + threadIdx.x;
    int b = node >> 10;
    int c = cnt[node];
    float acc = 0.f;
    for (int s = 0; s < c; ++s) {
        int j = ecol[node * ELLW + s];
        acc = fmaf(eval_[node * ELLW + s], g2[b * NN + j], acc);
    }
    out[node] = 1.f / (1.f + __expf(-acc));
}

extern "C" void kernel_launch(void* const* d_in, const int* in_sizes, int n_in,
                              void* d_out, int out_size, void* d_ws, size_t ws_size,
                              hipStream_t stream)
{
    const float* search = (const float*)d_in[0];
    const float* xcorr  = (const float*)d_in[1];
    const int*   pairs  = (const int*)d_in[2];
    const float* w1     = (const float*)d_in[3];
    const float* b1     = (const float*)d_in[4];
    const float* gamma  = (const float*)d_in[5];
    const float* beta   = (const float*)d_in[6];
    const float* w2     = (const float*)d_in[7];
    const float* b2     = (const float*)d_in[8];
    const float* gc1w   = (const float*)d_in[9];
    const float* gc2w   = (const float*)d_in[10];
    float* out = (float*)d_out;

    int E = in_sizes[2] / (BB * 2);   // 10068
    int nb = (E + 255) / 256;

    char* ws = (char*)d_ws;
    size_t off = 0;
    auto alloc = [&](size_t bytes) {
        size_t o = off;
        off += (bytes + 255) & ~(size_t)255;
        return o;
    };
    bf16*  hstore = (bf16*)(ws + alloc((size_t)BB * PH * E * 2));
    float* mu_a   = (float*)(ws + alloc(BB * PH * 4));
    float* rs_a   = (float*)(ws + alloc(BB * PH * 4));
    int*   cnt    = (int*)(ws + alloc(BB * NN * 4));
    int*   ecol   = (int*)(ws + alloc((size_t)BB * NN * ELLW * 4));
    float* eval_  = (float*)(ws + alloc((size_t)BB * NN * ELLW * 4));
    float* g1     = (float*)(ws + alloc((size_t)BB * NN * GH * 4));
    float* g2     = (float*)(ws + alloc(BB * NN * 4));
    (void)ws_size; (void)n_in; (void)out_size;

    k_zero_cnt<<<dim3((BB * NN + 255) / 256), dim3(256), 0, stream>>>(cnt);
    k_edge_h<<<dim3(BB * nb), dim3(256), 0, stream>>>(search, xcorr, pairs, w1, b1,
                                                      hstore, E, nb);
    k_bn_stats<<<dim3(BB * PH), dim3(256), 0, stream>>>(hstore, mu_a, rs_a, E);
    k_edge_val<<<dim3(BB * nb), dim3(256), 0, stream>>>(hstore, mu_a, rs_a, gamma,
                                                        beta, w2, b2, pairs, cnt,
                                                        ecol, eval_, E, nb);
    k_gc1<<<dim3(BB * 16), dim3(256), 0, stream>>>(search, xcorr, gc1w, g1);
    k_spmm1<<<dim3(BB * NN / 8), dim3(128), 0, stream>>>(g1, cnt, ecol, eval_, gc2w, g2);
    k_spmm2<<<dim3(BB * NN / 256), dim3(256), 0, stream>>>(g2, cnt, ecol, eval_, out);
}

// Round 3
// 353.142 us; speedup vs baseline: 1.0011x; 1.0011x over previous
//
#include <hip/hip_runtime.h>
#include <hip/hip_bf16.h>

#define BB 16
#define NN 1024
#define CS 256
#define CX 64
#define CC 320
#define PH 64
#define GH 128
#define ELLW 64
#define DROW 40   // LDS D-tile row stride in bf16 (32 data + 8 pad, 16B aligned)

typedef __hip_bfloat16 bf16;
typedef __attribute__((ext_vector_type(8))) __bf16 bfrag;   // 8 bf16 = 4 VGPRs
typedef __attribute__((ext_vector_type(4))) float v4f;

// ---------------- prep: pack W1 (hi/lo split) into B-frag order ----------
// Wfrag[ks][nt][lane][j] = w1[k][n], k=ks*32+(lane>>4)*8+j, n=nt*16+(lane&15)
__global__ __launch_bounds__(256) void k_prep(
    const float* __restrict__ w1, __bf16* __restrict__ whi,
    __bf16* __restrict__ wlo, int* __restrict__ cnt,
    float* __restrict__ Ssum, float* __restrict__ S2sum)
{
    int idx = blockIdx.x * 256 + threadIdx.x;
    if (idx < 10 * 4 * 64 * 8) {
        int j    = idx & 7;
        int lane = (idx >> 3) & 63;
        int nt   = (idx >> 9) & 3;
        int ks   = idx >> 11;
        int k = ks * 32 + (lane >> 4) * 8 + j;
        int n = nt * 16 + (lane & 15);
        float w = w1[k * PH + n];
        __bf16 h = (__bf16)w;
        whi[idx] = h;
        wlo[idx] = (__bf16)(w - (float)h);
    }
    if (idx < BB * NN) cnt[idx] = 0;
    if (idx < BB * PH) { Ssum[idx] = 0.f; S2sum[idx] = 0.f; }
}

// ------ stage 1: h = |f_i - f_j| @ W1  (split-bf16 MFMA) -> f32 [B,E,64] --
__global__ __launch_bounds__(256) void k_edge_gemm(
    const float* __restrict__ search, const float* __restrict__ xcorr,
    const int* __restrict__ pairs, const __bf16* __restrict__ whi,
    const __bf16* __restrict__ wlo, const float* __restrict__ b1,
    float* __restrict__ hstore, int E, int nb2)
{
    __shared__ __bf16 Dhi[256 * DROW];
    __shared__ __bf16 Dlo[256 * DROW];

    int b  = blockIdx.x / nb2;
    int e0 = (blockIdx.x % nb2) * 256;
    int t    = threadIdx.x;
    int wave = t >> 6, lane = t & 63;
    int q = lane >> 4, r = lane & 15;

    // gather edge for this thread
    int eg  = e0 + t;
    int egc = eg < E ? eg : E - 1;
    int i = pairs[((size_t)b * E + egc) * 2 + 0];
    int j = pairs[((size_t)b * E + egc) * 2 + 1];

    const float* sb = search + (size_t)b * CS * NN;
    const float* xb = xcorr + (size_t)b * CX * NN;
    const bfrag* wfh = (const bfrag*)whi;
    const bfrag* wfl = (const bfrag*)wlo;

    v4f acc[4][4];
    #pragma unroll
    for (int mt = 0; mt < 4; ++mt)
        #pragma unroll
        for (int nt = 0; nt < 4; ++nt) acc[mt][nt] = (v4f)0.f;

    #pragma unroll 1
    for (int ks = 0; ks < 10; ++ks) {
        if (ks) __syncthreads();
        const float* base = (ks < 8) ? (sb + (size_t)ks * 32 * NN)
                                     : (xb + (size_t)(ks - 8) * 32 * NN);
        // build hi/lo D tiles: thread t = edge row, 32 channels, b128 writes
        #pragma unroll
        for (int g = 0; g < 4; ++g) {
            bfrag hv, lv;
            #pragma unroll
            for (int kk = 0; kk < 8; ++kk) {
                int c = g * 8 + kk;
                float fi = base[c * NN + i];
                float fj = base[c * NN + j];
                float d = fabsf(fi - fj);
                __bf16 h = (__bf16)d;
                hv[kk] = h;
                lv[kk] = (__bf16)(d - (float)h);
            }
            *(bfrag*)&Dhi[t * DROW + g * 8] = hv;
            *(bfrag*)&Dlo[t * DROW + g * 8] = lv;
        }
        __syncthreads();

        // B fragments: coalesced 1KB loads (L1-resident after first use)
        bfrag bh[4], bl[4];
        #pragma unroll
        for (int nt = 0; nt < 4; ++nt) {
            bh[nt] = wfh[((ks * 4 + nt) << 6) + lane];
            bl[nt] = wfl[((ks * 4 + nt) << 6) + lane];
        }
        // A fragments from LDS
        bfrag ah[4], al[4];
        #pragma unroll
        for (int mt = 0; mt < 4; ++mt) {
            int o = ((wave * 4 + mt) * 16 + r) * DROW + q * 8;
            ah[mt] = *(const bfrag*)&Dhi[o];
            al[mt] = *(const bfrag*)&Dlo[o];
        }

        #pragma unroll
        for (int mt = 0; mt < 4; ++mt)
            #pragma unroll
            for (int nt = 0; nt < 4; ++nt) {
                acc[mt][nt] = __builtin_amdgcn_mfma_f32_16x16x32_bf16(
                    ah[mt], bh[nt], acc[mt][nt], 0, 0, 0);
                acc[mt][nt] = __builtin_amdgcn_mfma_f32_16x16x32_bf16(
                    ah[mt], bl[nt], acc[mt][nt], 0, 0, 0);
                acc[mt][nt] = __builtin_amdgcn_mfma_f32_16x16x32_bf16(
                    al[mt], bh[nt], acc[mt][nt], 0, 0, 0);
            }
    }

    // epilogue: bias + store f32 h[b][e][64]
    float b1v[4];
    #pragma unroll
    for (int nt = 0; nt < 4; ++nt) b1v[nt] = b1[nt * 16 + r];
    #pragma unroll
    for (int mt = 0; mt < 4; ++mt) {
        #pragma unroll
        for (int reg = 0; reg < 4; ++reg) {
            int e = e0 + (wave * 4 + mt) * 16 + q * 4 + reg;
            if (e < E) {
                float* hp = hstore + ((size_t)b * E + e) * PH + r;
                #pragma unroll
                for (int nt = 0; nt < 4; ++nt)
                    hp[nt * 16] = acc[mt][nt][reg] + b1v[nt];
            }
        }
    }
}

// ---------------- stage 2a: BN partial sums per (b, l) --------------------
__global__ __launch_bounds__(256) void k_bn_partial(
    const float* __restrict__ hstore, float* __restrict__ Ssum,
    float* __restrict__ S2sum, int E)
{
    int b = blockIdx.x >> 3;
    int p = blockIdx.x & 7;
    int chunk = (E + 7) / 8;
    int ebeg = p * chunk;
    int eend = min(E, ebeg + chunk);
    int wave = threadIdx.x >> 6, l = threadIdx.x & 63;

    float s = 0.f, s2 = 0.f;
    for (int e = ebeg + wave; e < eend; e += 4) {
        float v = hstore[((size_t)b * E + e) * PH + l];
        s += v; s2 += v * v;
    }
    __shared__ float ls[4][64], ls2[4][64];
    ls[wave][l] = s; ls2[wave][l] = s2;
    __syncthreads();
    if (threadIdx.x < 64) {
        float S  = ls[0][l] + ls[1][l] + ls[2][l] + ls[3][l];
        float S2 = ls2[0][l] + ls2[1][l] + ls2[2][l] + ls2[3][l];
        atomicAdd(&Ssum[b * PH + l], S);
        atomicAdd(&S2sum[b * PH + l], S2);
    }
}

// ---------------- stage 2b: fold BN into per-channel A,B coefs ------------
__global__ __launch_bounds__(256) void k_bn_final(
    const float* __restrict__ Ssum, const float* __restrict__ S2sum,
    const float* __restrict__ gamma, const float* __restrict__ beta,
    float* __restrict__ coefA, float* __restrict__ coefB, int E)
{
    int idx = blockIdx.x * 256 + threadIdx.x;
    if (idx >= BB * PH) return;
    int l = idx & 63;
    float mu = Ssum[idx] / E;
    float var = S2sum[idx] / E - mu * mu;
    float rs = rsqrtf(var + 1e-5f);
    float A = rs * gamma[l];
    coefA[idx] = A;
    coefB[idx] = beta[l] - mu * A;
}

// -------- stage 3: edge value (BN+ReLU+Linear+sigmoid) + ELL scatter -----
__global__ __launch_bounds__(256) void k_edge_val(
    const float* __restrict__ hstore, const float* __restrict__ coefA,
    const float* __restrict__ coefB, const float* __restrict__ w2,
    const float* __restrict__ b2, const int* __restrict__ pairs,
    int* __restrict__ cnt, int* __restrict__ ecol, float* __restrict__ eval_,
    int E, int nb)
{
    int b = blockIdx.x / nb;
    int e = (blockIdx.x % nb) * 256 + threadIdx.x;
    if (e >= E) return;
    const float4* hp = (const float4*)(hstore + ((size_t)b * E + e) * PH);
    const float* ca = coefA + b * PH;
    const float* cb = coefB + b * PH;
    float acc = 0.f;
    #pragma unroll
    for (int l4 = 0; l4 < 16; ++l4) {
        float4 v = hp[l4];
        float vv[4] = {v.x, v.y, v.z, v.w};
        #pragma unroll
        for (int c = 0; c < 4; ++c) {
            int l = l4 * 4 + c;
            float x = fmaf(vv[c], ca[l], cb[l]);
            x = x > 0.f ? x : 0.f;
            acc = fmaf(x, w2[l], acc);
        }
    }
    float edge = 1.f / (1.f + __expf(-(acc + b2[0])));
    const int* cp = pairs + ((size_t)b * E + e) * 2;
    int i = cp[0], j = cp[1];
    int row = b * NN + i;
    int slot = atomicAdd(&cnt[row], 1);
    if (slot < ELLW) {
        ecol[row * ELLW + slot]  = j;
        eval_[row * ELLW + slot] = edge;
    }
}

// ---------------- stage 4: g1 = node_feat @ gc1_w  [B*N,320]@[320,128] ----
__global__ __launch_bounds__(256) void k_gc1(
    const float* __restrict__ search, const float* __restrict__ xcorr,
    const float* __restrict__ w, float* __restrict__ g1)
{
    int b = blockIdx.x >> 4;
    int ntile = (blockIdx.x & 15) * 64;
    __shared__ float As[32 * 64];
    __shared__ float Wsh[32 * 128];
    int tid = threadIdx.x;
    int d0 = (tid & 15) * 8;
    int n0 = (tid >> 4) * 4;
    float Creg[4][8];
    #pragma unroll
    for (int ii = 0; ii < 4; ++ii)
        #pragma unroll
        for (int jj = 0; jj < 8; ++jj) Creg[ii][jj] = 0.f;

    const float* sb = search + (size_t)b * CS * NN;
    const float* xb = xcorr + (size_t)b * CX * NN;

    for (int k0 = 0; k0 < CC; k0 += 32) {
        #pragma unroll
        for (int f = 0; f < 8; ++f) {
            int idx = tid + f * 256;
            int cc = idx >> 6, nn = idx & 63;
            int c = k0 + cc;
            As[idx] = (c < CS) ? sb[c * NN + ntile + nn]
                               : xb[(c - CS) * NN + ntile + nn];
        }
        #pragma unroll
        for (int f = 0; f < 16; ++f) {
            int idx = tid + f * 256;
            int cc = idx >> 7, dd = idx & 127;
            Wsh[idx] = w[(k0 + cc) * GH + dd];
        }
        __syncthreads();
        #pragma unroll 1
        for (int cc = 0; cc < 32; ++cc) {
            const float* ap = &As[cc * 64 + n0];
            float a0 = ap[0], a1 = ap[1], a2 = ap[2], a3 = ap[3];
            const float* wp = &Wsh[cc * 128 + d0];
            float wv[8];
            #pragma unroll
            for (int jj = 0; jj < 8; ++jj) wv[jj] = wp[jj];
            #pragma unroll
            for (int jj = 0; jj < 8; ++jj) {
                Creg[0][jj] = fmaf(a0, wv[jj], Creg[0][jj]);
                Creg[1][jj] = fmaf(a1, wv[jj], Creg[1][jj]);
                Creg[2][jj] = fmaf(a2, wv[jj], Creg[2][jj]);
                Creg[3][jj] = fmaf(a3, wv[jj], Creg[3][jj]);
            }
        }
        __syncthreads();
    }
    #pragma unroll
    for (int ii = 0; ii < 4; ++ii) {
        size_t o = ((size_t)b * NN + ntile + n0 + ii) * GH + d0;
        #pragma unroll
        for (int jj = 0; jj < 8; ++jj) g1[o + jj] = Creg[ii][jj];
    }
}

// ------- stage 5: h1 = leaky(adj @ g1); g2 = h1 @ gc2_w  (fused) ---------
__global__ __launch_bounds__(128) void k_spmm1(
    const float* __restrict__ g1, const int* __restrict__ cnt,
    const int* __restrict__ ecol, const float* __restrict__ eval_,
    const float* __restrict__ w2g, float* __restrict__ g2)
{
    __shared__ float tmp[2];
    int tid = threadIdx.x;
    float wv = w2g[tid];
    for (int nn = 0; nn < 8; ++nn) {
        int node = blockIdx.x * 8 + nn;
        int b = node >> 10;
        int c = cnt[node];
        float acc = 0.f;
        for (int s = 0; s < c; ++s) {
            int j   = ecol[node * ELLW + s];
            float v = eval_[node * ELLW + s];
            acc = fmaf(v, g1[((size_t)b * NN + j) * GH + tid], acc);
        }
        float h1 = acc > 0.f ? acc : 0.2f * acc;
        float p = h1 * wv;
        #pragma unroll
        for (int off = 32; off >= 1; off >>= 1) p += __shfl_down(p, off, 64);
        if ((tid & 63) == 0) tmp[tid >> 6] = p;
        __syncthreads();
        if (tid == 0) g2[node] = tmp[0] + tmp[1];
        __syncthreads();
    }
}

// ------------- stage 6: out = sigmoid(adj @ g2) --------------------------
__global__ __launch_bounds__(256) void k_spmm2(
    const float* __restrict__ g2, const int* __restrict__ cnt,
    const int* __restrict__ ecol, const float* __restrict__ eval_,
    float* __restrict__ out)
{
    int node = blockIdx.x * 256 + threadIdx.x;
    int b = node >> 10;
    int c = cnt[node];
    float acc = 0.f;
    for (int s = 0; s < c; ++s) {
        int j = ecol[node * ELLW + s];
        acc = fmaf(eval_[node * ELLW + s], g2[b * NN + j], acc);
    }
    out[node] = 1.f / (1.f + __expf(-acc));
}

extern "C" void kernel_launch(void* const* d_in, const int* in_sizes, int n_in,
                              void* d_out, int out_size, void* d_ws, size_t ws_size,
                              hipStream_t stream)
{
    const float* search = (const float*)d_in[0];
    const float* xcorr  = (const float*)d_in[1];
    const int*   pairs  = (const int*)d_in[2];
    const float* w1     = (const float*)d_in[3];
    const float* b1     = (const float*)d_in[4];
    const float* gamma  = (const float*)d_in[5];
    const float* beta   = (const float*)d_in[6];
    const float* w2     = (const float*)d_in[7];
    const float* b2     = (const float*)d_in[8];
    const float* gc1w   = (const float*)d_in[9];
    const float* gc2w   = (const float*)d_in[10];
    float* out = (float*)d_out;

    int E = in_sizes[2] / (BB * 2);   // 10068
    int nb  = (E + 255) / 256;        // 40
    int nb2 = (E + 255) / 256;        // 40 edge tiles of 256

    char* ws = (char*)d_ws;
    size_t off = 0;
    auto alloc = [&](size_t bytes) {
        size_t o = off;
        off += (bytes + 255) & ~(size_t)255;
        return o;
    };
    __bf16* whi   = (__bf16*)(ws + alloc(10 * 4 * 64 * 8 * 2));
    __bf16* wlo   = (__bf16*)(ws + alloc(10 * 4 * 64 * 8 * 2));
    float* hstore = (float*)(ws + alloc((size_t)BB * E * PH * 4));
    float* Ssum   = (float*)(ws + alloc(BB * PH * 4));
    float* S2sum  = (float*)(ws + alloc(BB * PH * 4));
    float* coefA  = (float*)(ws + alloc(BB * PH * 4));
    float* coefB  = (float*)(ws + alloc(BB * PH * 4));
    int*   cnt    = (int*)(ws + alloc(BB * NN * 4));
    int*   ecol   = (int*)(ws + alloc((size_t)BB * NN * ELLW * 4));
    float* eval_  = (float*)(ws + alloc((size_t)BB * NN * ELLW * 4));
    float* g1     = (float*)(ws + alloc((size_t)BB * NN * GH * 4));
    float* g2     = (float*)(ws + alloc(BB * NN * 4));
    (void)ws_size; (void)n_in; (void)out_size;

    k_prep<<<dim3(80), dim3(256), 0, stream>>>(w1, whi, wlo, cnt, Ssum, S2sum);
    k_edge_gemm<<<dim3(BB * nb2), dim3(256), 0, stream>>>(search, xcorr, pairs,
                                                          whi, wlo, b1, hstore,
                                                          E, nb2);
    k_bn_partial<<<dim3(BB * 8), dim3(256), 0, stream>>>(hstore, Ssum, S2sum, E);
    k_bn_final<<<dim3(4), dim3(256), 0, stream>>>(Ssum, S2sum, gamma, beta,
                                                  coefA, coefB, E);
    k_edge_val<<<dim3(BB * nb), dim3(256), 0, stream>>>(hstore, coefA, coefB, w2,
                                                        b2, pairs, cnt, ecol, eval_,
                                                        E, nb);
    k_gc1<<<dim3(BB * 16), dim3(256), 0, stream>>>(search, xcorr, gc1w, g1);
    k_spmm1<<<dim3(BB * NN / 8), dim3(128), 0, stream>>>(g1, cnt, ecol, eval_, gc2w, g2);
    k_spmm2<<<dim3(BB * NN / 256), dim3(256), 0, stream>>>(g2, cnt, ecol, eval_, out);
}

// Round 4
// 250.484 us; speedup vs baseline: 1.4113x; 1.4098x over previous
//
#include <hip/hip_runtime.h>
#include <hip/hip_bf16.h>

#define BB 16
#define NN 1024
#define CS 256
#define CX 64
#define CC 320
#define PH 64
#define GH 128
#define ELLW 64
#define DROW 40   // LDS D-tile row stride in bf16 (32 data + 8 pad, 16B aligned)

typedef __hip_bfloat16 bf16;
typedef __attribute__((ext_vector_type(8))) __bf16 bfrag;   // 8 bf16 = 4 VGPRs
typedef __attribute__((ext_vector_type(4))) float v4f;

// ---------------- prep: pack W1 (hi/lo split) into B-frag order ----------
// Wfrag[ks][nt][lane][j] = w1[k][n], k=ks*32+(lane>>4)*8+j, n=nt*16+(lane&15)
__global__ __launch_bounds__(256) void k_prep(
    const float* __restrict__ w1, __bf16* __restrict__ whi,
    __bf16* __restrict__ wlo, int* __restrict__ cnt,
    float* __restrict__ Ssum, float* __restrict__ S2sum)
{
    int idx = blockIdx.x * 256 + threadIdx.x;
    if (idx < 10 * 4 * 64 * 8) {
        int j    = idx & 7;
        int lane = (idx >> 3) & 63;
        int nt   = (idx >> 9) & 3;
        int ks   = idx >> 11;
        int k = ks * 32 + (lane >> 4) * 8 + j;
        int n = nt * 16 + (lane & 15);
        float w = w1[k * PH + n];
        __bf16 h = (__bf16)w;
        whi[idx] = h;
        wlo[idx] = (__bf16)(w - (float)h);
    }
    if (idx < BB * NN) cnt[idx] = 0;
    if (idx < BB * PH) { Ssum[idx] = 0.f; S2sum[idx] = 0.f; }
}

// ------ stage 1: h = |f_i - f_j| @ W1 (split-bf16 MFMA) -> f32 [B,E,64]
//        + fused BN partial sums (block LDS reduce -> global atomicAdd) ----
__global__ __launch_bounds__(256) void k_edge_gemm(
    const float* __restrict__ search, const float* __restrict__ xcorr,
    const int* __restrict__ pairs, const __bf16* __restrict__ whi,
    const __bf16* __restrict__ wlo, const float* __restrict__ b1,
    float* __restrict__ hstore, float* __restrict__ Ssum,
    float* __restrict__ S2sum, int E, int nb2)
{
    __shared__ __bf16 Dhi[256 * DROW];
    __shared__ __bf16 Dlo[256 * DROW];
    __shared__ float sS[PH], sS2[PH];

    int b  = blockIdx.x / nb2;
    int e0 = (blockIdx.x % nb2) * 256;
    int t    = threadIdx.x;
    int wave = t >> 6, lane = t & 63;
    int q = lane >> 4, r = lane & 15;

    if (t < PH) { sS[t] = 0.f; sS2[t] = 0.f; }

    // gather edge for this thread
    int eg  = e0 + t;
    int egc = eg < E ? eg : E - 1;
    int i = pairs[((size_t)b * E + egc) * 2 + 0];
    int j = pairs[((size_t)b * E + egc) * 2 + 1];

    const float* sb = search + (size_t)b * CS * NN;
    const float* xb = xcorr + (size_t)b * CX * NN;
    const bfrag* wfh = (const bfrag*)whi;
    const bfrag* wfl = (const bfrag*)wlo;

    v4f acc[4][4];
    #pragma unroll
    for (int mt = 0; mt < 4; ++mt)
        #pragma unroll
        for (int nt = 0; nt < 4; ++nt) acc[mt][nt] = (v4f)0.f;

    #pragma unroll 1
    for (int ks = 0; ks < 10; ++ks) {
        if (ks) __syncthreads();
        const float* base = (ks < 8) ? (sb + (size_t)ks * 32 * NN)
                                     : (xb + (size_t)(ks - 8) * 32 * NN);
        // build hi/lo D tiles: thread t = edge row, 32 channels, b128 writes
        #pragma unroll
        for (int g = 0; g < 4; ++g) {
            bfrag hv, lv;
            #pragma unroll
            for (int kk = 0; kk < 8; ++kk) {
                int c = g * 8 + kk;
                float fi = base[c * NN + i];
                float fj = base[c * NN + j];
                float d = fabsf(fi - fj);
                __bf16 h = (__bf16)d;
                hv[kk] = h;
                lv[kk] = (__bf16)(d - (float)h);
            }
            *(bfrag*)&Dhi[t * DROW + g * 8] = hv;
            *(bfrag*)&Dlo[t * DROW + g * 8] = lv;
        }
        __syncthreads();

        // B fragments: coalesced 1KB loads (L1-resident after first use)
        bfrag bh[4], bl[4];
        #pragma unroll
        for (int nt = 0; nt < 4; ++nt) {
            bh[nt] = wfh[((ks * 4 + nt) << 6) + lane];
            bl[nt] = wfl[((ks * 4 + nt) << 6) + lane];
        }
        // A fragments from LDS
        bfrag ah[4], al[4];
        #pragma unroll
        for (int mt = 0; mt < 4; ++mt) {
            int o = ((wave * 4 + mt) * 16 + r) * DROW + q * 8;
            ah[mt] = *(const bfrag*)&Dhi[o];
            al[mt] = *(const bfrag*)&Dlo[o];
        }

        #pragma unroll
        for (int mt = 0; mt < 4; ++mt)
            #pragma unroll
            for (int nt = 0; nt < 4; ++nt) {
                acc[mt][nt] = __builtin_amdgcn_mfma_f32_16x16x32_bf16(
                    ah[mt], bh[nt], acc[mt][nt], 0, 0, 0);
                acc[mt][nt] = __builtin_amdgcn_mfma_f32_16x16x32_bf16(
                    ah[mt], bl[nt], acc[mt][nt], 0, 0, 0);
                acc[mt][nt] = __builtin_amdgcn_mfma_f32_16x16x32_bf16(
                    al[mt], bh[nt], acc[mt][nt], 0, 0, 0);
            }
    }

    // epilogue: bias + store f32 h[b][e][64] + BN partial sums
    float b1v[4];
    #pragma unroll
    for (int nt = 0; nt < 4; ++nt) b1v[nt] = b1[nt * 16 + r];

    float ps[4], ps2[4];
    #pragma unroll
    for (int nt = 0; nt < 4; ++nt) { ps[nt] = 0.f; ps2[nt] = 0.f; }

    #pragma unroll
    for (int mt = 0; mt < 4; ++mt) {
        #pragma unroll
        for (int reg = 0; reg < 4; ++reg) {
            int e = e0 + (wave * 4 + mt) * 16 + q * 4 + reg;
            if (e < E) {
                float* hp = hstore + ((size_t)b * E + e) * PH + r;
                #pragma unroll
                for (int nt = 0; nt < 4; ++nt) {
                    float v = acc[mt][nt][reg] + b1v[nt];
                    hp[nt * 16] = v;
                    ps[nt] += v;
                    ps2[nt] = fmaf(v, v, ps2[nt]);
                }
            }
        }
    }
    #pragma unroll
    for (int nt = 0; nt < 4; ++nt) {
        atomicAdd(&sS[nt * 16 + r],  ps[nt]);
        atomicAdd(&sS2[nt * 16 + r], ps2[nt]);
    }
    __syncthreads();
    if (t < PH) {
        atomicAdd(&Ssum[b * PH + t],  sS[t]);
        atomicAdd(&S2sum[b * PH + t], sS2[t]);
    }
}

// -- stage 3: BN-final (in-block) + edge value + ELL scatter --------------
__global__ __launch_bounds__(256) void k_edge_val(
    const float* __restrict__ hstore, const float* __restrict__ Ssum,
    const float* __restrict__ S2sum, const float* __restrict__ gamma,
    const float* __restrict__ beta, const float* __restrict__ w2,
    const float* __restrict__ b2, const int* __restrict__ pairs,
    int* __restrict__ cnt, int* __restrict__ ecol, float* __restrict__ eval_,
    int E, int nb)
{
    __shared__ float ca[PH], cb[PH];
    int b = blockIdx.x / nb;
    int e = (blockIdx.x % nb) * 256 + threadIdx.x;
    if (threadIdx.x < PH) {
        int l = threadIdx.x;
        float mu = Ssum[b * PH + l] / E;
        float var = S2sum[b * PH + l] / E - mu * mu;
        float A = rsqrtf(var + 1e-5f) * gamma[l];
        ca[l] = A;
        cb[l] = beta[l] - mu * A;
    }
    __syncthreads();
    if (e >= E) return;
    const float4* hp = (const float4*)(hstore + ((size_t)b * E + e) * PH);
    float acc = 0.f;
    #pragma unroll
    for (int l4 = 0; l4 < 16; ++l4) {
        float4 v = hp[l4];
        float vv[4] = {v.x, v.y, v.z, v.w};
        #pragma unroll
        for (int c = 0; c < 4; ++c) {
            int l = l4 * 4 + c;
            float x = fmaf(vv[c], ca[l], cb[l]);
            x = x > 0.f ? x : 0.f;
            acc = fmaf(x, w2[l], acc);
        }
    }
    float edge = 1.f / (1.f + __expf(-(acc + b2[0])));
    const int* cp = pairs + ((size_t)b * E + e) * 2;
    int i = cp[0], j = cp[1];
    int row = b * NN + i;
    int slot = atomicAdd(&cnt[row], 1);
    if (slot < ELLW) {
        ecol[row * ELLW + slot]  = j;
        eval_[row * ELLW + slot] = edge;
    }
}

// ---------------- stage 4: g1 = node_feat @ gc1_w  [B*N,320]@[320,128] ----
__global__ __launch_bounds__(256) void k_gc1(
    const float* __restrict__ search, const float* __restrict__ xcorr,
    const float* __restrict__ w, float* __restrict__ g1)
{
    int b = blockIdx.x >> 4;
    int ntile = (blockIdx.x & 15) * 64;
    __shared__ float As[32 * 64];
    __shared__ float Wsh[32 * 128];
    int tid = threadIdx.x;
    int d0 = (tid & 15) * 8;
    int n0 = (tid >> 4) * 4;
    float Creg[4][8];
    #pragma unroll
    for (int ii = 0; ii < 4; ++ii)
        #pragma unroll
        for (int jj = 0; jj < 8; ++jj) Creg[ii][jj] = 0.f;

    const float* sb = search + (size_t)b * CS * NN;
    const float* xb = xcorr + (size_t)b * CX * NN;

    for (int k0 = 0; k0 < CC; k0 += 32) {
        #pragma unroll
        for (int f = 0; f < 8; ++f) {
            int idx = tid + f * 256;
            int cc = idx >> 6, nn = idx & 63;
            int c = k0 + cc;
            As[idx] = (c < CS) ? sb[c * NN + ntile + nn]
                               : xb[(c - CS) * NN + ntile + nn];
        }
        #pragma unroll
        for (int f = 0; f < 16; ++f) {
            int idx = tid + f * 256;
            int cc = idx >> 7, dd = idx & 127;
            Wsh[idx] = w[(k0 + cc) * GH + dd];
        }
        __syncthreads();
        #pragma unroll 1
        for (int cc = 0; cc < 32; ++cc) {
            const float* ap = &As[cc * 64 + n0];
            float a0 = ap[0], a1 = ap[1], a2 = ap[2], a3 = ap[3];
            const float* wp = &Wsh[cc * 128 + d0];
            float wv[8];
            #pragma unroll
            for (int jj = 0; jj < 8; ++jj) wv[jj] = wp[jj];
            #pragma unroll
            for (int jj = 0; jj < 8; ++jj) {
                Creg[0][jj] = fmaf(a0, wv[jj], Creg[0][jj]);
                Creg[1][jj] = fmaf(a1, wv[jj], Creg[1][jj]);
                Creg[2][jj] = fmaf(a2, wv[jj], Creg[2][jj]);
                Creg[3][jj] = fmaf(a3, wv[jj], Creg[3][jj]);
            }
        }
        __syncthreads();
    }
    #pragma unroll
    for (int ii = 0; ii < 4; ++ii) {
        size_t o = ((size_t)b * NN + ntile + n0 + ii) * GH + d0;
        #pragma unroll
        for (int jj = 0; jj < 8; ++jj) g1[o + jj] = Creg[ii][jj];
    }
}

// ------- stage 5: h1 = leaky(adj @ g1); g2 = h1 @ gc2_w (1 node/block) ---
__global__ __launch_bounds__(128) void k_spmm1(
    const float* __restrict__ g1, const int* __restrict__ cnt,
    const int* __restrict__ ecol, const float* __restrict__ eval_,
    const float* __restrict__ w2g, float* __restrict__ g2)
{
    __shared__ float tmp[2];
    int tid = threadIdx.x;
    int node = blockIdx.x;
    int b = node >> 10;
    float wv = w2g[tid];
    int c = cnt[node];
    float acc = 0.f;
    for (int s = 0; s < c; ++s) {
        int j   = ecol[node * ELLW + s];
        float v = eval_[node * ELLW + s];
        acc = fmaf(v, g1[((size_t)b * NN + j) * GH + tid], acc);
    }
    float h1 = acc > 0.f ? acc : 0.2f * acc;
    float p = h1 * wv;
    #pragma unroll
    for (int off = 32; off >= 1; off >>= 1) p += __shfl_down(p, off, 64);
    if ((tid & 63) == 0) tmp[tid >> 6] = p;
    __syncthreads();
    if (tid == 0) g2[node] = tmp[0] + tmp[1];
}

// ------------- stage 6: out = sigmoid(adj @ g2) --------------------------
__global__ __launch_bounds__(256) void k_spmm2(
    const float* __restrict__ g2, const int* __restrict__ cnt,
    const int* __restrict__ ecol, const float* __restrict__ eval_,
    float* __restrict__ out)
{
    int node = blockIdx.x * 256 + threadIdx.x;
    int b = node >> 10;
    int c = cnt[node];
    float acc = 0.f;
    for (int s = 0; s < c; ++s) {
        int j = ecol[node * ELLW + s];
        acc = fmaf(eval_[node * ELLW + s], g2[b * NN + j], acc);
    }
    out[node] = 1.f / (1.f + __expf(-acc));
}

extern "C" void kernel_launch(void* const* d_in, const int* in_sizes, int n_in,
                              void* d_out, int out_size, void* d_ws, size_t ws_size,
                              hipStream_t stream)
{
    const float* search = (const float*)d_in[0];
    const float* xcorr  = (const float*)d_in[1];
    const int*   pairs  = (const int*)d_in[2];
    const float* w1     = (const float*)d_in[3];
    const float* b1     = (const float*)d_in[4];
    const float* gamma  = (const float*)d_in[5];
    const float* beta   = (const float*)d_in[6];
    const float* w2     = (const float*)d_in[7];
    const float* b2     = (const float*)d_in[8];
    const float* gc1w   = (const float*)d_in[9];
    const float* gc2w   = (const float*)d_in[10];
    float* out = (float*)d_out;

    int E = in_sizes[2] / (BB * 2);   // 10068
    int nb  = (E + 255) / 256;        // 40
    int nb2 = (E + 255) / 256;        // 40 edge tiles of 256

    char* ws = (char*)d_ws;
    size_t off = 0;
    auto alloc = [&](size_t bytes) {
        size_t o = off;
        off += (bytes + 255) & ~(size_t)255;
        return o;
    };
    __bf16* whi   = (__bf16*)(ws + alloc(10 * 4 * 64 * 8 * 2));
    __bf16* wlo   = (__bf16*)(ws + alloc(10 * 4 * 64 * 8 * 2));
    float* hstore = (float*)(ws + alloc((size_t)BB * E * PH * 4));
    float* Ssum   = (float*)(ws + alloc(BB * PH * 4));
    float* S2sum  = (float*)(ws + alloc(BB * PH * 4));
    int*   cnt    = (int*)(ws + alloc(BB * NN * 4));
    int*   ecol   = (int*)(ws + alloc((size_t)BB * NN * ELLW * 4));
    float* eval_  = (float*)(ws + alloc((size_t)BB * NN * ELLW * 4));
    float* g1     = (float*)(ws + alloc((size_t)BB * NN * GH * 4));
    float* g2     = (float*)(ws + alloc(BB * NN * 4));
    (void)ws_size; (void)n_in; (void)out_size;

    k_prep<<<dim3(80), dim3(256), 0, stream>>>(w1, whi, wlo, cnt, Ssum, S2sum);
    k_edge_gemm<<<dim3(BB * nb2), dim3(256), 0, stream>>>(search, xcorr, pairs,
                                                          whi, wlo, b1, hstore,
                                                          Ssum, S2sum, E, nb2);
    k_edge_val<<<dim3(BB * nb), dim3(256), 0, stream>>>(hstore, Ssum, S2sum,
                                                        gamma, beta, w2, b2,
                                                        pairs, cnt, ecol, eval_,
                                                        E, nb);
    k_gc1<<<dim3(BB * 16), dim3(256), 0, stream>>>(search, xcorr, gc1w, g1);
    k_spmm1<<<dim3(BB * NN), dim3(128), 0, stream>>>(g1, cnt, ecol, eval_, gc2w, g2);
    k_spmm2<<<dim3(BB * NN / 256), dim3(256), 0, stream>>>(g2, cnt, ecol, eval_, out);
}

// Round 5
// 240.431 us; speedup vs baseline: 1.4703x; 1.0418x over previous
//
#include <hip/hip_runtime.h>
#include <hip/hip_bf16.h>

#define BB 16
#define NN 1024
#define CS 256
#define CX 64
#define CC 320
#define PH 64
#define GH 128
#define ELLW 64
#define MTILE 128   // edges per block in k_edge_gemm

typedef __hip_bfloat16 bf16;
typedef __attribute__((ext_vector_type(8))) __bf16 bfrag;   // 8 bf16 = 4 VGPRs
typedef __attribute__((ext_vector_type(4))) float v4f;

// ---------------- prep: pack W1 (hi/lo split) into B-frag order ----------
// Wfrag[ks][nt][lane][j] = w1[k][n], k=ks*32+(lane>>4)*8+j, n=nt*16+(lane&15)
__global__ __launch_bounds__(256) void k_prep(
    const float* __restrict__ w1, __bf16* __restrict__ whi,
    __bf16* __restrict__ wlo, int* __restrict__ cnt,
    float* __restrict__ Ssum, float* __restrict__ S2sum)
{
    int idx = blockIdx.x * 256 + threadIdx.x;
    if (idx < 10 * 4 * 64 * 8) {
        int j    = idx & 7;
        int lane = (idx >> 3) & 63;
        int nt   = (idx >> 9) & 3;
        int ks   = idx >> 11;
        int k = ks * 32 + (lane >> 4) * 8 + j;
        int n = nt * 16 + (lane & 15);
        float w = w1[k * PH + n];
        __bf16 h = (__bf16)w;
        whi[idx] = h;
        wlo[idx] = (__bf16)(w - (float)h);
    }
    if (idx < BB * NN) cnt[idx] = 0;
    if (idx < BB * PH) { Ssum[idx] = 0.f; S2sum[idx] = 0.f; }
}

// ------ stage 1: h = |f_i - f_j| @ W1 (split-bf16 MFMA) -> f32 [B,E,64]
//   Direct per-lane A-fragment gather: NO LDS staging, NO K-loop barriers.
//   Wave w owns mtiles 2w,2w+1; lane(q,r) = edge mtile*16+r, ch q*8..q*8+7.
//   + fused BN partial sums (LDS reduce -> global atomicAdd).
__global__ __launch_bounds__(256, 3) void k_edge_gemm(
    const float* __restrict__ search, const float* __restrict__ xcorr,
    const int* __restrict__ pairs, const __bf16* __restrict__ whi,
    const __bf16* __restrict__ wlo, const float* __restrict__ b1,
    float* __restrict__ hstore, float* __restrict__ Ssum,
    float* __restrict__ S2sum, int E, int nb2)
{
    __shared__ float sS[PH], sS2[PH];

    int b  = blockIdx.x / nb2;
    int e0 = (blockIdx.x % nb2) * MTILE;
    int t    = threadIdx.x;
    int wave = t >> 6, lane = t & 63;
    int q = lane >> 4, r = lane & 15;

    if (t < PH) { sS[t] = 0.f; sS2[t] = 0.f; }

    // edge (i,j) per mtile owned by this lane
    int iA[2], jA[2];
    #pragma unroll
    for (int mt = 0; mt < 2; ++mt) {
        int e = e0 + (wave * 2 + mt) * 16 + r;
        int ec = e < E ? e : E - 1;
        iA[mt] = pairs[((size_t)b * E + ec) * 2 + 0];
        jA[mt] = pairs[((size_t)b * E + ec) * 2 + 1];
    }

    const float* sb = search + (size_t)b * CS * NN;
    const float* xb = xcorr + (size_t)b * CX * NN;
    const bfrag* wfh = (const bfrag*)whi;
    const bfrag* wfl = (const bfrag*)wlo;

    v4f acc[2][4];
    #pragma unroll
    for (int mt = 0; mt < 2; ++mt)
        #pragma unroll
        for (int nt = 0; nt < 4; ++nt) acc[mt][nt] = (v4f)0.f;

    // double-buffered raw gathers: 16 ch-pairs per mtile slice
    float fi[2][2][8], fj[2][2][8];

    auto LOAD = [&](int ks, int buf) {
        const float* base = (ks < 8) ? (sb + (size_t)ks * 32 * NN)
                                     : (xb + (size_t)(ks - 8) * 32 * NN);
        const float* bq = base + q * 8 * NN;
        #pragma unroll
        for (int mt = 0; mt < 2; ++mt)
            #pragma unroll
            for (int kk = 0; kk < 8; ++kk) {
                fi[buf][mt][kk] = bq[kk * NN + iA[mt]];
                fj[buf][mt][kk] = bq[kk * NN + jA[mt]];
            }
    };

    LOAD(0, 0);
    #pragma unroll
    for (int ks = 0; ks < 10; ++ks) {
        int cur = ks & 1;
        if (ks < 9) LOAD(ks + 1, cur ^ 1);

        // convert to hi/lo A-fragments
        bfrag ah[2], al[2];
        #pragma unroll
        for (int mt = 0; mt < 2; ++mt)
            #pragma unroll
            for (int kk = 0; kk < 8; ++kk) {
                float d = fabsf(fi[cur][mt][kk] - fj[cur][mt][kk]);
                __bf16 h = (__bf16)d;
                ah[mt][kk] = h;
                al[mt][kk] = (__bf16)(d - (float)h);
            }

        #pragma unroll
        for (int nt = 0; nt < 4; ++nt) {
            bfrag bh = wfh[((ks * 4 + nt) << 6) + lane];
            bfrag bl = wfl[((ks * 4 + nt) << 6) + lane];
            #pragma unroll
            for (int mt = 0; mt < 2; ++mt) {
                acc[mt][nt] = __builtin_amdgcn_mfma_f32_16x16x32_bf16(
                    ah[mt], bh, acc[mt][nt], 0, 0, 0);
                acc[mt][nt] = __builtin_amdgcn_mfma_f32_16x16x32_bf16(
                    ah[mt], bl, acc[mt][nt], 0, 0, 0);
                acc[mt][nt] = __builtin_amdgcn_mfma_f32_16x16x32_bf16(
                    al[mt], bh, acc[mt][nt], 0, 0, 0);
            }
        }
    }

    // epilogue: bias + store f32 h[b][e][64] + BN partial sums
    float b1v[4];
    #pragma unroll
    for (int nt = 0; nt < 4; ++nt) b1v[nt] = b1[nt * 16 + r];

    float ps[4], ps2[4];
    #pragma unroll
    for (int nt = 0; nt < 4; ++nt) { ps[nt] = 0.f; ps2[nt] = 0.f; }

    #pragma unroll
    for (int mt = 0; mt < 2; ++mt) {
        #pragma unroll
        for (int reg = 0; reg < 4; ++reg) {
            int e = e0 + (wave * 2 + mt) * 16 + q * 4 + reg;
            if (e < E) {
                float* hp = hstore + ((size_t)b * E + e) * PH + r;
                #pragma unroll
                for (int nt = 0; nt < 4; ++nt) {
                    float v = acc[mt][nt][reg] + b1v[nt];
                    hp[nt * 16] = v;
                    ps[nt] += v;
                    ps2[nt] = fmaf(v, v, ps2[nt]);
                }
            }
        }
    }
    #pragma unroll
    for (int nt = 0; nt < 4; ++nt) {
        atomicAdd(&sS[nt * 16 + r],  ps[nt]);
        atomicAdd(&sS2[nt * 16 + r], ps2[nt]);
    }
    __syncthreads();
    if (t < PH) {
        atomicAdd(&Ssum[b * PH + t],  sS[t]);
        atomicAdd(&S2sum[b * PH + t], sS2[t]);
    }
}

// -- stage 3: BN-final (in-block) + edge value + ELL scatter --------------
__global__ __launch_bounds__(256) void k_edge_val(
    const float* __restrict__ hstore, const float* __restrict__ Ssum,
    const float* __restrict__ S2sum, const float* __restrict__ gamma,
    const float* __restrict__ beta, const float* __restrict__ w2,
    const float* __restrict__ b2, const int* __restrict__ pairs,
    int* __restrict__ cnt, int* __restrict__ ecol, float* __restrict__ eval_,
    int E, int nb)
{
    __shared__ float ca[PH], cb[PH];
    int b = blockIdx.x / nb;
    int e = (blockIdx.x % nb) * 256 + threadIdx.x;
    if (threadIdx.x < PH) {
        int l = threadIdx.x;
        float mu = Ssum[b * PH + l] / E;
        float var = S2sum[b * PH + l] / E - mu * mu;
        float A = rsqrtf(var + 1e-5f) * gamma[l];
        ca[l] = A;
        cb[l] = beta[l] - mu * A;
    }
    __syncthreads();
    if (e >= E) return;
    const float4* hp = (const float4*)(hstore + ((size_t)b * E + e) * PH);
    float acc = 0.f;
    #pragma unroll
    for (int l4 = 0; l4 < 16; ++l4) {
        float4 v = hp[l4];
        float vv[4] = {v.x, v.y, v.z, v.w};
        #pragma unroll
        for (int c = 0; c < 4; ++c) {
            int l = l4 * 4 + c;
            float x = fmaf(vv[c], ca[l], cb[l]);
            x = x > 0.f ? x : 0.f;
            acc = fmaf(x, w2[l], acc);
        }
    }
    float edge = 1.f / (1.f + __expf(-(acc + b2[0])));
    const int* cp = pairs + ((size_t)b * E + e) * 2;
    int i = cp[0], j = cp[1];
    int row = b * NN + i;
    int slot = atomicAdd(&cnt[row], 1);
    if (slot < ELLW) {
        ecol[row * ELLW + slot]  = j;
        eval_[row * ELLW + slot] = edge;
    }
}

// ---------------- stage 4: g1 = node_feat @ gc1_w  [B*N,320]@[320,128] ----
__global__ __launch_bounds__(256) void k_gc1(
    const float* __restrict__ search, const float* __restrict__ xcorr,
    const float* __restrict__ w, float* __restrict__ g1)
{
    int b = blockIdx.x >> 4;
    int ntile = (blockIdx.x & 15) * 64;
    __shared__ float As[32 * 64];
    __shared__ float Wsh[32 * 128];
    int tid = threadIdx.x;
    int d0 = (tid & 15) * 8;
    int n0 = (tid >> 4) * 4;
    float Creg[4][8];
    #pragma unroll
    for (int ii = 0; ii < 4; ++ii)
        #pragma unroll
        for (int jj = 0; jj < 8; ++jj) Creg[ii][jj] = 0.f;

    const float* sb = search + (size_t)b * CS * NN;
    const float* xb = xcorr + (size_t)b * CX * NN;

    for (int k0 = 0; k0 < CC; k0 += 32) {
        #pragma unroll
        for (int f = 0; f < 8; ++f) {
            int idx = tid + f * 256;
            int cc = idx >> 6, nn = idx & 63;
            int c = k0 + cc;
            As[idx] = (c < CS) ? sb[c * NN + ntile + nn]
                               : xb[(c - CS) * NN + ntile + nn];
        }
        #pragma unroll
        for (int f = 0; f < 16; ++f) {
            int idx = tid + f * 256;
            int cc = idx >> 7, dd = idx & 127;
            Wsh[idx] = w[(k0 + cc) * GH + dd];
        }
        __syncthreads();
        #pragma unroll 1
        for (int cc = 0; cc < 32; ++cc) {
            const float* ap = &As[cc * 64 + n0];
            float a0 = ap[0], a1 = ap[1], a2 = ap[2], a3 = ap[3];
            const float* wp = &Wsh[cc * 128 + d0];
            float wv[8];
            #pragma unroll
            for (int jj = 0; jj < 8; ++jj) wv[jj] = wp[jj];
            #pragma unroll
            for (int jj = 0; jj < 8; ++jj) {
                Creg[0][jj] = fmaf(a0, wv[jj], Creg[0][jj]);
                Creg[1][jj] = fmaf(a1, wv[jj], Creg[1][jj]);
                Creg[2][jj] = fmaf(a2, wv[jj], Creg[2][jj]);
                Creg[3][jj] = fmaf(a3, wv[jj], Creg[3][jj]);
            }
        }
        __syncthreads();
    }
    #pragma unroll
    for (int ii = 0; ii < 4; ++ii) {
        size_t o = ((size_t)b * NN + ntile + n0 + ii) * GH + d0;
        #pragma unroll
        for (int jj = 0; jj < 8; ++jj) g1[o + jj] = Creg[ii][jj];
    }
}

// ------- stage 5: h1 = leaky(adj @ g1); g2 = h1 @ gc2_w (1 node/block) ---
__global__ __launch_bounds__(128) void k_spmm1(
    const float* __restrict__ g1, const int* __restrict__ cnt,
    const int* __restrict__ ecol, const float* __restrict__ eval_,
    const float* __restrict__ w2g, float* __restrict__ g2)
{
    __shared__ float tmp[2];
    int tid = threadIdx.x;
    int node = blockIdx.x;
    int b = node >> 10;
    float wv = w2g[tid];
    int c = cnt[node];
    float acc = 0.f;
    for (int s = 0; s < c; ++s) {
        int j   = ecol[node * ELLW + s];
        float v = eval_[node * ELLW + s];
        acc = fmaf(v, g1[((size_t)b * NN + j) * GH + tid], acc);
    }
    float h1 = acc > 0.f ? acc : 0.2f * acc;
    float p = h1 * wv;
    #pragma unroll
    for (int off = 32; off >= 1; off >>= 1) p += __shfl_down(p, off, 64);
    if ((tid & 63) == 0) tmp[tid >> 6] = p;
    __syncthreads();
    if (tid == 0) g2[node] = tmp[0] + tmp[1];
}

// ------------- stage 6: out = sigmoid(adj @ g2) (1 wave/node, lane=slot) -
__global__ __launch_bounds__(64) void k_spmm2(
    const float* __restrict__ g2, const int* __restrict__ cnt,
    const int* __restrict__ ecol, const float* __restrict__ eval_,
    float* __restrict__ out)
{
    int node = blockIdx.x;
    int b = node >> 10;
    int lane = threadIdx.x;
    int c = cnt[node];
    float p = 0.f;
    if (lane < c) {
        int j = ecol[node * ELLW + lane];
        p = eval_[node * ELLW + lane] * g2[b * NN + j];
    }
    #pragma unroll
    for (int off = 32; off >= 1; off >>= 1) p += __shfl_down(p, off, 64);
    if (lane == 0) out[node] = 1.f / (1.f + __expf(-p));
}

extern "C" void kernel_launch(void* const* d_in, const int* in_sizes, int n_in,
                              void* d_out, int out_size, void* d_ws, size_t ws_size,
                              hipStream_t stream)
{
    const float* search = (const float*)d_in[0];
    const float* xcorr  = (const float*)d_in[1];
    const int*   pairs  = (const int*)d_in[2];
    const float* w1     = (const float*)d_in[3];
    const float* b1     = (const float*)d_in[4];
    const float* gamma  = (const float*)d_in[5];
    const float* beta   = (const float*)d_in[6];
    const float* w2     = (const float*)d_in[7];
    const float* b2     = (const float*)d_in[8];
    const float* gc1w   = (const float*)d_in[9];
    const float* gc2w   = (const float*)d_in[10];
    float* out = (float*)d_out;

    int E = in_sizes[2] / (BB * 2);      // 10068
    int nb  = (E + 255) / 256;           // 40
    int nb2 = (E + MTILE - 1) / MTILE;   // 79

    char* ws = (char*)d_ws;
    size_t off = 0;
    auto alloc = [&](size_t bytes) {
        size_t o = off;
        off += (bytes + 255) & ~(size_t)255;
        return o;
    };
    __bf16* whi   = (__bf16*)(ws + alloc(10 * 4 * 64 * 8 * 2));
    __bf16* wlo   = (__bf16*)(ws + alloc(10 * 4 * 64 * 8 * 2));
    float* hstore = (float*)(ws + alloc((size_t)BB * E * PH * 4));
    float* Ssum   = (float*)(ws + alloc(BB * PH * 4));
    float* S2sum  = (float*)(ws + alloc(BB * PH * 4));
    int*   cnt    = (int*)(ws + alloc(BB * NN * 4));
    int*   ecol   = (int*)(ws + alloc((size_t)BB * NN * ELLW * 4));
    float* eval_  = (float*)(ws + alloc((size_t)BB * NN * ELLW * 4));
    float* g1     = (float*)(ws + alloc((size_t)BB * NN * GH * 4));
    float* g2     = (float*)(ws + alloc(BB * NN * 4));
    (void)ws_size; (void)n_in; (void)out_size;

    k_prep<<<dim3(80), dim3(256), 0, stream>>>(w1, whi, wlo, cnt, Ssum, S2sum);
    k_edge_gemm<<<dim3(BB * nb2), dim3(256), 0, stream>>>(search, xcorr, pairs,
                                                          whi, wlo, b1, hstore,
                                                          Ssum, S2sum, E, nb2);
    k_edge_val<<<dim3(BB * nb), dim3(256), 0, stream>>>(hstore, Ssum, S2sum,
                                                        gamma, beta, w2, b2,
                                                        pairs, cnt, ecol, eval_,
                                                        E, nb);
    k_gc1<<<dim3(BB * 16), dim3(256), 0, stream>>>(search, xcorr, gc1w, g1);
    k_spmm1<<<dim3(BB * NN), dim3(128), 0, stream>>>(g1, cnt, ecol, eval_, gc2w, g2);
    k_spmm2<<<dim3(BB * NN), dim3(64), 0, stream>>>(g2, cnt, ecol, eval_, out);
}

// Round 6
// 228.203 us; speedup vs baseline: 1.5491x; 1.0536x over previous
//
#include <hip/hip_runtime.h>
#include <hip/hip_bf16.h>

#define BB 16
#define NN 1024
#define CS 256
#define CX 64
#define CC 320
#define PH 64
#define GH 128
#define ELLW 64
#define MTILE 128   // edges per block in k_edge_gemm

typedef __hip_bfloat16 bf16;
typedef __attribute__((ext_vector_type(8))) __bf16 bfrag;   // 8 bf16 = 4 VGPRs
typedef __attribute__((ext_vector_type(4))) float v4f;

// ---------------- prep: pack W1 + gc1_w (hi/lo split) into B-frag order --
// frag[ks][nt][lane][j] = w[k][n], k=ks*32+(lane>>4)*8+j, n=nt*16+(lane&15)
__global__ __launch_bounds__(256) void k_prep(
    const float* __restrict__ w1, const float* __restrict__ gc1w,
    __bf16* __restrict__ whi, __bf16* __restrict__ wlo,
    __bf16* __restrict__ gwhi, __bf16* __restrict__ gwlo,
    int* __restrict__ cnt, float* __restrict__ Ssum, float* __restrict__ S2sum)
{
    int idx = blockIdx.x * 256 + threadIdx.x;
    if (idx < 10 * 4 * 64 * 8) {          // W1: PH=64 -> 4 ntiles
        int j    = idx & 7;
        int lane = (idx >> 3) & 63;
        int nt   = (idx >> 9) & 3;
        int ks   = idx >> 11;
        int k = ks * 32 + (lane >> 4) * 8 + j;
        int n = nt * 16 + (lane & 15);
        float w = w1[k * PH + n];
        __bf16 h = (__bf16)w;
        whi[idx] = h;
        wlo[idx] = (__bf16)(w - (float)h);
    }
    if (idx < 10 * 8 * 64 * 8) {          // gc1_w: GH=128 -> 8 ntiles
        int j    = idx & 7;
        int lane = (idx >> 3) & 63;
        int nt   = (idx >> 9) & 7;
        int ks   = idx >> 12;
        int k = ks * 32 + (lane >> 4) * 8 + j;
        int n = nt * 16 + (lane & 15);
        float w = gc1w[k * GH + n];
        __bf16 h = (__bf16)w;
        gwhi[idx] = h;
        gwlo[idx] = (__bf16)(w - (float)h);
    }
    if (idx < BB * NN) cnt[idx] = 0;
    if (idx < BB * PH) { Ssum[idx] = 0.f; S2sum[idx] = 0.f; }
}

// ---------------- transpose: [B,C,N] -> featT [B,N,C] f32 ----------------
__global__ __launch_bounds__(256) void k_transpose(
    const float* __restrict__ search, const float* __restrict__ xcorr,
    float* __restrict__ featT)
{
    __shared__ float tile[32][33];
    int blk = blockIdx.x;
    int b   = blk / 320;
    int rem = blk % 320;
    int ct  = rem >> 5;       // 10 channel tiles
    int ntl = rem & 31;       // 32 node tiles
    int tid = threadIdx.x;
    int cl = tid >> 5, nl = tid & 31;
    const float* sb = search + (size_t)b * CS * NN;
    const float* xb = xcorr + (size_t)b * CX * NN;
    #pragma unroll
    for (int f = 0; f < 4; ++f) {
        int c = ct * 32 + cl + f * 8;
        int n = ntl * 32 + nl;
        float v = (c < CS) ? sb[(size_t)c * NN + n] : xb[(size_t)(c - CS) * NN + n];
        tile[cl + f * 8][nl] = v;
    }
    __syncthreads();
    #pragma unroll
    for (int f = 0; f < 4; ++f) {
        int nr = cl + f * 8;
        int cc = nl;
        featT[((size_t)b * NN + ntl * 32 + nr) * CC + ct * 32 + cc] = tile[cc][nr];
    }
}

// ------ stage 1: h = |f_i - f_j| @ W1 (split-bf16 MFMA) -> bf16 [B,E,64]
//   featT gathers: 8 dwordx4 per lane per K-step, no LDS, no barriers.
//   + fused BN partial sums (LDS reduce -> global atomicAdd).
__global__ __launch_bounds__(256, 3) void k_edge_gemm(
    const float* __restrict__ featT, const int* __restrict__ pairs,
    const __bf16* __restrict__ whi, const __bf16* __restrict__ wlo,
    const float* __restrict__ b1, bf16* __restrict__ hstore,
    float* __restrict__ Ssum, float* __restrict__ S2sum, int E, int nb2)
{
    __shared__ float sS[PH], sS2[PH];

    int b  = blockIdx.x / nb2;
    int e0 = (blockIdx.x % nb2) * MTILE;
    int t    = threadIdx.x;
    int wave = t >> 6, lane = t & 63;
    int q = lane >> 4, r = lane & 15;

    if (t < PH) { sS[t] = 0.f; sS2[t] = 0.f; }

    // node rows for the 2 mtile edges this lane owns
    const float* pI[2];
    const float* pJ[2];
    #pragma unroll
    for (int mt = 0; mt < 2; ++mt) {
        int e = e0 + (wave * 2 + mt) * 16 + r;
        int ec = e < E ? e : E - 1;
        int i = pairs[((size_t)b * E + ec) * 2 + 0];
        int j = pairs[((size_t)b * E + ec) * 2 + 1];
        pI[mt] = featT + ((size_t)b * NN + i) * CC + q * 8;
        pJ[mt] = featT + ((size_t)b * NN + j) * CC + q * 8;
    }

    const bfrag* wfh = (const bfrag*)whi;
    const bfrag* wfl = (const bfrag*)wlo;

    v4f acc[2][4];
    #pragma unroll
    for (int mt = 0; mt < 2; ++mt)
        #pragma unroll
        for (int nt = 0; nt < 4; ++nt) acc[mt][nt] = (v4f)0.f;

    float fi[2][2][8], fj[2][2][8];

    auto LOAD = [&](int ks, int buf) {
        #pragma unroll
        for (int mt = 0; mt < 2; ++mt) {
            const float4* a = (const float4*)(pI[mt] + ks * 32);
            const float4* c = (const float4*)(pJ[mt] + ks * 32);
            *(float4*)&fi[buf][mt][0] = a[0];
            *(float4*)&fi[buf][mt][4] = a[1];
            *(float4*)&fj[buf][mt][0] = c[0];
            *(float4*)&fj[buf][mt][4] = c[1];
        }
    };

    LOAD(0, 0);
    #pragma unroll
    for (int ks = 0; ks < 10; ++ks) {
        int cur = ks & 1;
        if (ks < 9) LOAD(ks + 1, cur ^ 1);

        bfrag ah[2], al[2];
        #pragma unroll
        for (int mt = 0; mt < 2; ++mt)
            #pragma unroll
            for (int kk = 0; kk < 8; ++kk) {
                float d = fabsf(fi[cur][mt][kk] - fj[cur][mt][kk]);
                __bf16 h = (__bf16)d;
                ah[mt][kk] = h;
                al[mt][kk] = (__bf16)(d - (float)h);
            }

        #pragma unroll
        for (int nt = 0; nt < 4; ++nt) {
            bfrag bh = wfh[((ks * 4 + nt) << 6) + lane];
            bfrag bl = wfl[((ks * 4 + nt) << 6) + lane];
            #pragma unroll
            for (int mt = 0; mt < 2; ++mt) {
                acc[mt][nt] = __builtin_amdgcn_mfma_f32_16x16x32_bf16(
                    ah[mt], bh, acc[mt][nt], 0, 0, 0);
                acc[mt][nt] = __builtin_amdgcn_mfma_f32_16x16x32_bf16(
                    ah[mt], bl, acc[mt][nt], 0, 0, 0);
                acc[mt][nt] = __builtin_amdgcn_mfma_f32_16x16x32_bf16(
                    al[mt], bh, acc[mt][nt], 0, 0, 0);
            }
        }
    }

    // epilogue: bias + store bf16 h[b][e][64] + BN partial sums (f32)
    float b1v[4];
    #pragma unroll
    for (int nt = 0; nt < 4; ++nt) b1v[nt] = b1[nt * 16 + r];

    float ps[4], ps2[4];
    #pragma unroll
    for (int nt = 0; nt < 4; ++nt) { ps[nt] = 0.f; ps2[nt] = 0.f; }

    #pragma unroll
    for (int mt = 0; mt < 2; ++mt) {
        #pragma unroll
        for (int reg = 0; reg < 4; ++reg) {
            int e = e0 + (wave * 2 + mt) * 16 + q * 4 + reg;
            if (e < E) {
                bf16* hp = hstore + ((size_t)b * E + e) * PH + r;
                #pragma unroll
                for (int nt = 0; nt < 4; ++nt) {
                    float v = acc[mt][nt][reg] + b1v[nt];
                    hp[nt * 16] = __float2bfloat16(v);
                    ps[nt] += v;
                    ps2[nt] = fmaf(v, v, ps2[nt]);
                }
            }
        }
    }
    #pragma unroll
    for (int nt = 0; nt < 4; ++nt) {
        atomicAdd(&sS[nt * 16 + r],  ps[nt]);
        atomicAdd(&sS2[nt * 16 + r], ps2[nt]);
    }
    __syncthreads();
    if (t < PH) {
        atomicAdd(&Ssum[b * PH + t],  sS[t]);
        atomicAdd(&S2sum[b * PH + t], sS2[t]);
    }
}

// -- stage 3: BN-final (in-block) + edge value + ELL scatter --------------
__global__ __launch_bounds__(256) void k_edge_val(
    const bf16* __restrict__ hstore, const float* __restrict__ Ssum,
    const float* __restrict__ S2sum, const float* __restrict__ gamma,
    const float* __restrict__ beta, const float* __restrict__ w2,
    const float* __restrict__ b2, const int* __restrict__ pairs,
    int* __restrict__ cnt, int* __restrict__ ecol, float* __restrict__ eval_,
    int E, int nb)
{
    __shared__ float ca[PH], cb[PH];
    int b = blockIdx.x / nb;
    int e = (blockIdx.x % nb) * 256 + threadIdx.x;
    if (threadIdx.x < PH) {
        int l = threadIdx.x;
        float mu = Ssum[b * PH + l] / E;
        float var = S2sum[b * PH + l] / E - mu * mu;
        float A = rsqrtf(var + 1e-5f) * gamma[l];
        ca[l] = A;
        cb[l] = beta[l] - mu * A;
    }
    __syncthreads();
    if (e >= E) return;
    const bfrag* hp = (const bfrag*)(hstore + ((size_t)b * E + e) * PH);
    float acc = 0.f;
    #pragma unroll
    for (int l8 = 0; l8 < 8; ++l8) {
        bfrag hv = hp[l8];
        #pragma unroll
        for (int c = 0; c < 8; ++c) {
            int l = l8 * 8 + c;
            float x = fmaf((float)hv[c], ca[l], cb[l]);
            x = x > 0.f ? x : 0.f;
            acc = fmaf(x, w2[l], acc);
        }
    }
    float edge = 1.f / (1.f + __expf(-(acc + b2[0])));
    const int* cp = pairs + ((size_t)b * E + e) * 2;
    int i = cp[0], j = cp[1];
    int row = b * NN + i;
    int slot = atomicAdd(&cnt[row], 1);
    if (slot < ELLW) {
        ecol[row * ELLW + slot]  = j;
        eval_[row * ELLW + slot] = edge;
    }
}

// ------ stage 4: g1 = featT @ gc1_w  (split-bf16 MFMA, 64 nodes/block) ---
__global__ __launch_bounds__(256) void k_gc1(
    const float* __restrict__ featT, const __bf16* __restrict__ gwhi,
    const __bf16* __restrict__ gwlo, float* __restrict__ g1)
{
    int m0 = blockIdx.x * 64;          // global node base (b folded in)
    int t = threadIdx.x, wave = t >> 6, lane = t & 63;
    int q = lane >> 4, r = lane & 15;
    const float* fp = featT + (size_t)(m0 + wave * 16 + r) * CC + q * 8;
    const bfrag* wh = (const bfrag*)gwhi;
    const bfrag* wl = (const bfrag*)gwlo;

    v4f acc[8];
    #pragma unroll
    for (int nt = 0; nt < 8; ++nt) acc[nt] = (v4f)0.f;

    float fa[2][8];
    auto LOADA = [&](int ks, int buf) {
        const float4* p = (const float4*)(fp + ks * 32);
        *(float4*)&fa[buf][0] = p[0];
        *(float4*)&fa[buf][4] = p[1];
    };

    LOADA(0, 0);
    #pragma unroll
    for (int ks = 0; ks < 10; ++ks) {
        int cur = ks & 1;
        if (ks < 9) LOADA(ks + 1, cur ^ 1);
        bfrag ah, al;
        #pragma unroll
        for (int kk = 0; kk < 8; ++kk) {
            float d = fa[cur][kk];
            __bf16 h = (__bf16)d;
            ah[kk] = h;
            al[kk] = (__bf16)(d - (float)h);
        }
        #pragma unroll
        for (int nt = 0; nt < 8; ++nt) {
            bfrag bh = wh[((ks * 8 + nt) << 6) + lane];
            bfrag bl = wl[((ks * 8 + nt) << 6) + lane];
            acc[nt] = __builtin_amdgcn_mfma_f32_16x16x32_bf16(ah, bh, acc[nt], 0, 0, 0);
            acc[nt] = __builtin_amdgcn_mfma_f32_16x16x32_bf16(ah, bl, acc[nt], 0, 0, 0);
            acc[nt] = __builtin_amdgcn_mfma_f32_16x16x32_bf16(al, bh, acc[nt], 0, 0, 0);
        }
    }
    #pragma unroll
    for (int nt = 0; nt < 8; ++nt) {
        #pragma unroll
        for (int reg = 0; reg < 4; ++reg) {
            int m = m0 + wave * 16 + q * 4 + reg;
            g1[(size_t)m * GH + nt * 16 + r] = acc[nt][reg];
        }
    }
}

// ------- stage 5: h1 = leaky(adj @ g1); g2 = h1 @ gc2_w (1 node/block) ---
__global__ __launch_bounds__(128) void k_spmm1(
    const float* __restrict__ g1, const int* __restrict__ cnt,
    const int* __restrict__ ecol, const float* __restrict__ eval_,
    const float* __restrict__ w2g, float* __restrict__ g2)
{
    __shared__ float tmp[2];
    int tid = threadIdx.x;
    int node = blockIdx.x;
    int b = node >> 10;
    float wv = w2g[tid];
    int c = cnt[node];
    const int* ec = ecol + (size_t)node * ELLW;
    const float* ev = eval_ + (size_t)node * ELLW;
    float acc = 0.f;
    int s = 0;
    for (; s + 4 <= c; s += 4) {
        int j0 = ec[s], j1 = ec[s + 1], j2 = ec[s + 2], j3 = ec[s + 3];
        float v0 = ev[s], v1 = ev[s + 1], v2 = ev[s + 2], v3 = ev[s + 3];
        float a0 = g1[((size_t)b * NN + j0) * GH + tid];
        float a1 = g1[((size_t)b * NN + j1) * GH + tid];
        float a2 = g1[((size_t)b * NN + j2) * GH + tid];
        float a3 = g1[((size_t)b * NN + j3) * GH + tid];
        acc = fmaf(v0, a0, acc); acc = fmaf(v1, a1, acc);
        acc = fmaf(v2, a2, acc); acc = fmaf(v3, a3, acc);
    }
    for (; s < c; ++s) {
        int j = ec[s];
        acc = fmaf(ev[s], g1[((size_t)b * NN + j) * GH + tid], acc);
    }
    float h1 = acc > 0.f ? acc : 0.2f * acc;
    float p = h1 * wv;
    #pragma unroll
    for (int off = 32; off >= 1; off >>= 1) p += __shfl_down(p, off, 64);
    if ((tid & 63) == 0) tmp[tid >> 6] = p;
    __syncthreads();
    if (tid == 0) g2[node] = tmp[0] + tmp[1];
}

// ------------- stage 6: out = sigmoid(adj @ g2) (1 wave/node, lane=slot) -
__global__ __launch_bounds__(64) void k_spmm2(
    const float* __restrict__ g2, const int* __restrict__ cnt,
    const int* __restrict__ ecol, const float* __restrict__ eval_,
    float* __restrict__ out)
{
    int node = blockIdx.x;
    int b = node >> 10;
    int lane = threadIdx.x;
    int c = cnt[node];
    float p = 0.f;
    if (lane < c) {
        int j = ecol[(size_t)node * ELLW + lane];
        p = eval_[(size_t)node * ELLW + lane] * g2[b * NN + j];
    }
    #pragma unroll
    for (int off = 32; off >= 1; off >>= 1) p += __shfl_down(p, off, 64);
    if (lane == 0) out[node] = 1.f / (1.f + __expf(-p));
}

extern "C" void kernel_launch(void* const* d_in, const int* in_sizes, int n_in,
                              void* d_out, int out_size, void* d_ws, size_t ws_size,
                              hipStream_t stream)
{
    const float* search = (const float*)d_in[0];
    const float* xcorr  = (const float*)d_in[1];
    const int*   pairs  = (const int*)d_in[2];
    const float* w1     = (const float*)d_in[3];
    const float* b1     = (const float*)d_in[4];
    const float* gamma  = (const float*)d_in[5];
    const float* beta   = (const float*)d_in[6];
    const float* w2     = (const float*)d_in[7];
    const float* b2     = (const float*)d_in[8];
    const float* gc1w   = (const float*)d_in[9];
    const float* gc2w   = (const float*)d_in[10];
    float* out = (float*)d_out;

    int E = in_sizes[2] / (BB * 2);      // 10068
    int nb  = (E + 255) / 256;           // 40
    int nb2 = (E + MTILE - 1) / MTILE;   // 79

    char* ws = (char*)d_ws;
    size_t off = 0;
    auto alloc = [&](size_t bytes) {
        size_t o = off;
        off += (bytes + 255) & ~(size_t)255;
        return o;
    };
    __bf16* whi   = (__bf16*)(ws + alloc(10 * 4 * 64 * 8 * 2));
    __bf16* wlo   = (__bf16*)(ws + alloc(10 * 4 * 64 * 8 * 2));
    __bf16* gwhi  = (__bf16*)(ws + alloc(10 * 8 * 64 * 8 * 2));
    __bf16* gwlo  = (__bf16*)(ws + alloc(10 * 8 * 64 * 8 * 2));
    float* featT  = (float*)(ws + alloc((size_t)BB * NN * CC * 4));
    bf16*  hstore = (bf16*)(ws + alloc((size_t)BB * E * PH * 2));
    float* Ssum   = (float*)(ws + alloc(BB * PH * 4));
    float* S2sum  = (float*)(ws + alloc(BB * PH * 4));
    int*   cnt    = (int*)(ws + alloc(BB * NN * 4));
    int*   ecol   = (int*)(ws + alloc((size_t)BB * NN * ELLW * 4));
    float* eval_  = (float*)(ws + alloc((size_t)BB * NN * ELLW * 4));
    float* g1     = (float*)(ws + alloc((size_t)BB * NN * GH * 4));
    float* g2     = (float*)(ws + alloc(BB * NN * 4));
    (void)ws_size; (void)n_in; (void)out_size;

    k_prep<<<dim3(160), dim3(256), 0, stream>>>(w1, gc1w, whi, wlo, gwhi, gwlo,
                                                cnt, Ssum, S2sum);
    k_transpose<<<dim3(BB * 320), dim3(256), 0, stream>>>(search, xcorr, featT);
    k_edge_gemm<<<dim3(BB * nb2), dim3(256), 0, stream>>>(featT, pairs, whi, wlo,
                                                          b1, hstore, Ssum, S2sum,
                                                          E, nb2);
    k_edge_val<<<dim3(BB * nb), dim3(256), 0, stream>>>(hstore, Ssum, S2sum,
                                                        gamma, beta, w2, b2,
                                                        pairs, cnt, ecol, eval_,
                                                        E, nb);
    k_gc1<<<dim3(BB * NN / 64), dim3(256), 0, stream>>>(featT, gwhi, gwlo, g1);
    k_spmm1<<<dim3(BB * NN), dim3(128), 0, stream>>>(g1, cnt, ecol, eval_, gc2w, g2);
    k_spmm2<<<dim3(BB * NN), dim3(64), 0, stream>>>(g2, cnt, ecol, eval_, out);
}

// Round 7
// 222.313 us; speedup vs baseline: 1.5902x; 1.0265x over previous
//
#include <hip/hip_runtime.h>
#include <hip/hip_bf16.h>

#define BB 16
#define NN 1024
#define CS 256
#define CX 64
#define CC 320
#define PH 64
#define GH 128
#define ELLW 64
#define MTILE 64    // edges per block in k_edge_gemm (1 mtile per wave)

typedef __hip_bfloat16 bf16;
typedef __attribute__((ext_vector_type(8))) __bf16 bfrag;   // 8 bf16 = 4 VGPRs
typedef __attribute__((ext_vector_type(4))) float v4f;

// ---------------- prep: pack W1 + gc1_w (hi/lo split) into B-frag order --
// frag[ks][nt][lane][j] = w[k][n], k=ks*32+(lane>>4)*8+j, n=nt*16+(lane&15)
__global__ __launch_bounds__(256) void k_prep(
    const float* __restrict__ w1, const float* __restrict__ gc1w,
    __bf16* __restrict__ whi, __bf16* __restrict__ wlo,
    __bf16* __restrict__ gwhi, __bf16* __restrict__ gwlo,
    int* __restrict__ cnt, float* __restrict__ Ssum, float* __restrict__ S2sum)
{
    int idx = blockIdx.x * 256 + threadIdx.x;
    if (idx < 10 * 4 * 64 * 8) {          // W1: PH=64 -> 4 ntiles
        int j    = idx & 7;
        int lane = (idx >> 3) & 63;
        int nt   = (idx >> 9) & 3;
        int ks   = idx >> 11;
        int k = ks * 32 + (lane >> 4) * 8 + j;
        int n = nt * 16 + (lane & 15);
        float w = w1[k * PH + n];
        __bf16 h = (__bf16)w;
        whi[idx] = h;
        wlo[idx] = (__bf16)(w - (float)h);
    }
    if (idx < 10 * 8 * 64 * 8) {          // gc1_w: GH=128 -> 8 ntiles
        int j    = idx & 7;
        int lane = (idx >> 3) & 63;
        int nt   = (idx >> 9) & 7;
        int ks   = idx >> 12;
        int k = ks * 32 + (lane >> 4) * 8 + j;
        int n = nt * 16 + (lane & 15);
        float w = gc1w[k * GH + n];
        __bf16 h = (__bf16)w;
        gwhi[idx] = h;
        gwlo[idx] = (__bf16)(w - (float)h);
    }
    if (idx < BB * NN) cnt[idx] = 0;
    if (idx < BB * PH) { Ssum[idx] = 0.f; S2sum[idx] = 0.f; }
}

// ---------------- transpose: [B,C,N] -> featT [B,N,C] f32 ----------------
// blockIdx % BB = image  ->  image b pinned to XCD b%8 (round-robin)
__global__ __launch_bounds__(256) void k_transpose(
    const float* __restrict__ search, const float* __restrict__ xcorr,
    float* __restrict__ featT)
{
    __shared__ float tile[32][33];
    int blk = blockIdx.x;
    int b   = blk % BB;
    int rem = blk / BB;       // 0..319
    int ct  = rem >> 5;       // 10 channel tiles
    int ntl = rem & 31;       // 32 node tiles
    int tid = threadIdx.x;
    int cl = tid >> 5, nl = tid & 31;
    const float* sb = search + (size_t)b * CS * NN;
    const float* xb = xcorr + (size_t)b * CX * NN;
    #pragma unroll
    for (int f = 0; f < 4; ++f) {
        int c = ct * 32 + cl + f * 8;
        int n = ntl * 32 + nl;
        float v = (c < CS) ? sb[(size_t)c * NN + n] : xb[(size_t)(c - CS) * NN + n];
        tile[cl + f * 8][nl] = v;
    }
    __syncthreads();
    #pragma unroll
    for (int f = 0; f < 4; ++f) {
        int nr = cl + f * 8;
        int cc = nl;
        featT[((size_t)b * NN + ntl * 32 + nr) * CC + ct * 32 + cc] = tile[cc][nr];
    }
}

// ------ stage 1: h = |f_i - f_j| @ W1 (split-bf16 MFMA) -> f32 [B,E,64]
//   1 mtile (16 edges) per wave; 3-buffer 2-deep prefetch pipeline.
//   blockIdx % BB = image -> XCD-local featT (L2 resident, ~1.3 MB/image).
__global__ __launch_bounds__(256, 4) void k_edge_gemm(
    const float* __restrict__ featT, const int* __restrict__ pairs,
    const __bf16* __restrict__ whi, const __bf16* __restrict__ wlo,
    const float* __restrict__ b1, float* __restrict__ hstore,
    float* __restrict__ Ssum, float* __restrict__ S2sum, int E)
{
    __shared__ float sS[PH], sS2[PH];

    int idx = blockIdx.x;
    int b  = idx % BB;
    int e0 = (idx / BB) * MTILE;
    int t    = threadIdx.x;
    int wave = t >> 6, lane = t & 63;
    int q = lane >> 4, r = lane & 15;

    if (t < PH) { sS[t] = 0.f; sS2[t] = 0.f; }

    int eg = e0 + wave * 16 + r;
    int ec = eg < E ? eg : E - 1;
    int i = pairs[((size_t)b * E + ec) * 2 + 0];
    int j = pairs[((size_t)b * E + ec) * 2 + 1];
    const float* pI = featT + ((size_t)b * NN + i) * CC + q * 8;
    const float* pJ = featT + ((size_t)b * NN + j) * CC + q * 8;

    const bfrag* wfh = (const bfrag*)whi;
    const bfrag* wfl = (const bfrag*)wlo;

    v4f acc[4];
    #pragma unroll
    for (int nt = 0; nt < 4; ++nt) acc[nt] = (v4f)0.f;

    float fi[3][8], fj[3][8];
    auto LOAD = [&](int ks, int buf) {
        const float4* a = (const float4*)(pI + ks * 32);
        const float4* c = (const float4*)(pJ + ks * 32);
        *(float4*)&fi[buf][0] = a[0];
        *(float4*)&fi[buf][4] = a[1];
        *(float4*)&fj[buf][0] = c[0];
        *(float4*)&fj[buf][4] = c[1];
    };

    LOAD(0, 0);
    LOAD(1, 1);
    #pragma unroll
    for (int ks = 0; ks < 10; ++ks) {
        int cur = ks % 3;
        if (ks + 2 < 10) LOAD(ks + 2, (ks + 2) % 3);

        bfrag ah, al;
        #pragma unroll
        for (int kk = 0; kk < 8; ++kk) {
            float d = fabsf(fi[cur][kk] - fj[cur][kk]);
            __bf16 h = (__bf16)d;
            ah[kk] = h;
            al[kk] = (__bf16)(d - (float)h);
        }

        #pragma unroll
        for (int nt = 0; nt < 4; ++nt) {
            bfrag bh = wfh[((ks * 4 + nt) << 6) + lane];
            bfrag bl = wfl[((ks * 4 + nt) << 6) + lane];
            acc[nt] = __builtin_amdgcn_mfma_f32_16x16x32_bf16(ah, bh, acc[nt], 0, 0, 0);
            acc[nt] = __builtin_amdgcn_mfma_f32_16x16x32_bf16(ah, bl, acc[nt], 0, 0, 0);
            acc[nt] = __builtin_amdgcn_mfma_f32_16x16x32_bf16(al, bh, acc[nt], 0, 0, 0);
        }
    }

    // epilogue: bias + store f32 h[b][e][64] + BN partial sums
    float b1v[4];
    #pragma unroll
    for (int nt = 0; nt < 4; ++nt) b1v[nt] = b1[nt * 16 + r];

    float ps[4], ps2[4];
    #pragma unroll
    for (int nt = 0; nt < 4; ++nt) { ps[nt] = 0.f; ps2[nt] = 0.f; }

    #pragma unroll
    for (int reg = 0; reg < 4; ++reg) {
        int e = e0 + wave * 16 + q * 4 + reg;
        if (e < E) {
            float* hp = hstore + ((size_t)b * E + e) * PH + r;
            #pragma unroll
            for (int nt = 0; nt < 4; ++nt) {
                float v = acc[nt][reg] + b1v[nt];
                hp[nt * 16] = v;
                ps[nt] += v;
                ps2[nt] = fmaf(v, v, ps2[nt]);
            }
        }
    }
    #pragma unroll
    for (int nt = 0; nt < 4; ++nt) {
        atomicAdd(&sS[nt * 16 + r],  ps[nt]);
        atomicAdd(&sS2[nt * 16 + r], ps2[nt]);
    }
    __syncthreads();
    if (t < PH) {
        atomicAdd(&Ssum[b * PH + t],  sS[t]);
        atomicAdd(&S2sum[b * PH + t], sS2[t]);
    }
}

// -- stage 3: BN-final (in-block) + edge value + ELL scatter --------------
__global__ __launch_bounds__(256) void k_edge_val(
    const float* __restrict__ hstore, const float* __restrict__ Ssum,
    const float* __restrict__ S2sum, const float* __restrict__ gamma,
    const float* __restrict__ beta, const float* __restrict__ w2,
    const float* __restrict__ b2, const int* __restrict__ pairs,
    int* __restrict__ cnt, int* __restrict__ ecol, float* __restrict__ eval_,
    int E)
{
    __shared__ float ca[PH], cb[PH];
    int b = blockIdx.x % BB;
    int e = (blockIdx.x / BB) * 256 + threadIdx.x;
    if (threadIdx.x < PH) {
        int l = threadIdx.x;
        float mu = Ssum[b * PH + l] / E;
        float var = S2sum[b * PH + l] / E - mu * mu;
        float A = rsqrtf(var + 1e-5f) * gamma[l];
        ca[l] = A;
        cb[l] = beta[l] - mu * A;
    }
    __syncthreads();
    if (e >= E) return;
    const float4* hp = (const float4*)(hstore + ((size_t)b * E + e) * PH);
    float acc = 0.f;
    #pragma unroll
    for (int l4 = 0; l4 < 16; ++l4) {
        float4 v = hp[l4];
        float vv[4] = {v.x, v.y, v.z, v.w};
        #pragma unroll
        for (int c = 0; c < 4; ++c) {
            int l = l4 * 4 + c;
            float x = fmaf(vv[c], ca[l], cb[l]);
            x = x > 0.f ? x : 0.f;
            acc = fmaf(x, w2[l], acc);
        }
    }
    float edge = 1.f / (1.f + __expf(-(acc + b2[0])));
    const int* cp = pairs + ((size_t)b * E + e) * 2;
    int i = cp[0], j = cp[1];
    int row = b * NN + i;
    int slot = atomicAdd(&cnt[row], 1);
    if (slot < ELLW) {
        ecol[row * ELLW + slot]  = j;
        eval_[row * ELLW + slot] = edge;
    }
}

// ------ stage 4: g1 = featT @ gc1_w  (split-bf16 MFMA, 64 nodes/block) ---
__global__ __launch_bounds__(256) void k_gc1(
    const float* __restrict__ featT, const __bf16* __restrict__ gwhi,
    const __bf16* __restrict__ gwlo, float* __restrict__ g1)
{
    int b = blockIdx.x % BB;
    int m0 = b * NN + (blockIdx.x / BB) * 64;
    int t = threadIdx.x, wave = t >> 6, lane = t & 63;
    int q = lane >> 4, r = lane & 15;
    const float* fp = featT + (size_t)(m0 + wave * 16 + r) * CC + q * 8;
    const bfrag* wh = (const bfrag*)gwhi;
    const bfrag* wl = (const bfrag*)gwlo;

    v4f acc[8];
    #pragma unroll
    for (int nt = 0; nt < 8; ++nt) acc[nt] = (v4f)0.f;

    float fa[2][8];
    auto LOADA = [&](int ks, int buf) {
        const float4* p = (const float4*)(fp + ks * 32);
        *(float4*)&fa[buf][0] = p[0];
        *(float4*)&fa[buf][4] = p[1];
    };

    LOADA(0, 0);
    #pragma unroll
    for (int ks = 0; ks < 10; ++ks) {
        int cur = ks & 1;
        if (ks < 9) LOADA(ks + 1, cur ^ 1);
        bfrag ah, al;
        #pragma unroll
        for (int kk = 0; kk < 8; ++kk) {
            float d = fa[cur][kk];
            __bf16 h = (__bf16)d;
            ah[kk] = h;
            al[kk] = (__bf16)(d - (float)h);
        }
        #pragma unroll
        for (int nt = 0; nt < 8; ++nt) {
            bfrag bh = wh[((ks * 8 + nt) << 6) + lane];
            bfrag bl = wl[((ks * 8 + nt) << 6) + lane];
            acc[nt] = __builtin_amdgcn_mfma_f32_16x16x32_bf16(ah, bh, acc[nt], 0, 0, 0);
            acc[nt] = __builtin_amdgcn_mfma_f32_16x16x32_bf16(ah, bl, acc[nt], 0, 0, 0);
            acc[nt] = __builtin_amdgcn_mfma_f32_16x16x32_bf16(al, bh, acc[nt], 0, 0, 0);
        }
    }
    #pragma unroll
    for (int nt = 0; nt < 8; ++nt) {
        #pragma unroll
        for (int reg = 0; reg < 4; ++reg) {
            int m = m0 + wave * 16 + q * 4 + reg;
            g1[(size_t)m * GH + nt * 16 + r] = acc[nt][reg];
        }
    }
}

// ------- stage 5: h1 = leaky(adj @ g1); g2 = h1 @ gc2_w (1 node/block) ---
__global__ __launch_bounds__(128) void k_spmm1(
    const float* __restrict__ g1, const int* __restrict__ cnt,
    const int* __restrict__ ecol, const float* __restrict__ eval_,
    const float* __restrict__ w2g, float* __restrict__ g2)
{
    __shared__ float tmp[2];
    int tid = threadIdx.x;
    int b = blockIdx.x % BB;
    int node = b * NN + blockIdx.x / BB;
    float wv = w2g[tid];
    int c = cnt[node];
    const int* ec = ecol + (size_t)node * ELLW;
    const float* ev = eval_ + (size_t)node * ELLW;
    float acc = 0.f;
    int s = 0;
    for (; s + 4 <= c; s += 4) {
        int j0 = ec[s], j1 = ec[s + 1], j2 = ec[s + 2], j3 = ec[s + 3];
        float v0 = ev[s], v1 = ev[s + 1], v2 = ev[s + 2], v3 = ev[s + 3];
        float a0 = g1[((size_t)b * NN + j0) * GH + tid];
        float a1 = g1[((size_t)b * NN + j1) * GH + tid];
        float a2 = g1[((size_t)b * NN + j2) * GH + tid];
        float a3 = g1[((size_t)b * NN + j3) * GH + tid];
        acc = fmaf(v0, a0, acc); acc = fmaf(v1, a1, acc);
        acc = fmaf(v2, a2, acc); acc = fmaf(v3, a3, acc);
    }
    for (; s < c; ++s) {
        int j = ec[s];
        acc = fmaf(ev[s], g1[((size_t)b * NN + j) * GH + tid], acc);
    }
    float h1 = acc > 0.f ? acc : 0.2f * acc;
    float p = h1 * wv;
    #pragma unroll
    for (int off = 32; off >= 1; off >>= 1) p += __shfl_down(p, off, 64);
    if ((tid & 63) == 0) tmp[tid >> 6] = p;
    __syncthreads();
    if (tid == 0) g2[node] = tmp[0] + tmp[1];
}

// ------------- stage 6: out = sigmoid(adj @ g2) (1 wave/node, lane=slot) -
__global__ __launch_bounds__(64) void k_spmm2(
    const float* __restrict__ g2, const int* __restrict__ cnt,
    const int* __restrict__ ecol, const float* __restrict__ eval_,
    float* __restrict__ out)
{
    int b = blockIdx.x % BB;
    int node = b * NN + blockIdx.x / BB;
    int lane = threadIdx.x;
    int c = cnt[node];
    float p = 0.f;
    if (lane < c) {
        int j = ecol[(size_t)node * ELLW + lane];
        p = eval_[(size_t)node * ELLW + lane] * g2[b * NN + j];
    }
    #pragma unroll
    for (int off = 32; off >= 1; off >>= 1) p += __shfl_down(p, off, 64);
    if (lane == 0) out[node] = 1.f / (1.f + __expf(-p));
}

extern "C" void kernel_launch(void* const* d_in, const int* in_sizes, int n_in,
                              void* d_out, int out_size, void* d_ws, size_t ws_size,
                              hipStream_t stream)
{
    const float* search = (const float*)d_in[0];
    const float* xcorr  = (const float*)d_in[1];
    const int*   pairs  = (const int*)d_in[2];
    const float* w1     = (const float*)d_in[3];
    const float* b1     = (const float*)d_in[4];
    const float* gamma  = (const float*)d_in[5];
    const float* beta   = (const float*)d_in[6];
    const float* w2     = (const float*)d_in[7];
    const float* b2     = (const float*)d_in[8];
    const float* gc1w   = (const float*)d_in[9];
    const float* gc2w   = (const float*)d_in[10];
    float* out = (float*)d_out;

    int E = in_sizes[2] / (BB * 2);      // 10068
    int nb  = (E + 255) / 256;           // 40
    int nb2 = (E + MTILE - 1) / MTILE;   // 158

    char* ws = (char*)d_ws;
    size_t off = 0;
    auto alloc = [&](size_t bytes) {
        size_t o = off;
        off += (bytes + 255) & ~(size_t)255;
        return o;
    };
    __bf16* whi   = (__bf16*)(ws + alloc(10 * 4 * 64 * 8 * 2));
    __bf16* wlo   = (__bf16*)(ws + alloc(10 * 4 * 64 * 8 * 2));
    __bf16* gwhi  = (__bf16*)(ws + alloc(10 * 8 * 64 * 8 * 2));
    __bf16* gwlo  = (__bf16*)(ws + alloc(10 * 8 * 64 * 8 * 2));
    float* featT  = (float*)(ws + alloc((size_t)BB * NN * CC * 4));
    float* hstore = (float*)(ws + alloc((size_t)BB * E * PH * 4));
    float* Ssum   = (float*)(ws + alloc(BB * PH * 4));
    float* S2sum  = (float*)(ws + alloc(BB * PH * 4));
    int*   cnt    = (int*)(ws + alloc(BB * NN * 4));
    int*   ecol   = (int*)(ws + alloc((size_t)BB * NN * ELLW * 4));
    float* eval_  = (float*)(ws + alloc((size_t)BB * NN * ELLW * 4));
    float* g1     = (float*)(ws + alloc((size_t)BB * NN * GH * 4));
    float* g2     = (float*)(ws + alloc(BB * NN * 4));
    (void)ws_size; (void)n_in; (void)out_size;

    k_prep<<<dim3(160), dim3(256), 0, stream>>>(w1, gc1w, whi, wlo, gwhi, gwlo,
                                                cnt, Ssum, S2sum);
    k_transpose<<<dim3(BB * 320), dim3(256), 0, stream>>>(search, xcorr, featT);
    k_edge_gemm<<<dim3(BB * nb2), dim3(256), 0, stream>>>(featT, pairs, whi, wlo,
                                                          b1, hstore, Ssum, S2sum, E);
    k_edge_val<<<dim3(BB * nb), dim3(256), 0, stream>>>(hstore, Ssum, S2sum,
                                                        gamma, beta, w2, b2,
                                                        pairs, cnt, ecol, eval_, E);
    k_gc1<<<dim3(BB * NN / 64), dim3(256), 0, stream>>>(featT, gwhi, gwlo, g1);
    k_spmm1<<<dim3(BB * NN), dim3(128), 0, stream>>>(g1, cnt, ecol, eval_, gc2w, g2);
    k_spmm2<<<dim3(BB * NN), dim3(64), 0, stream>>>(g2, cnt, ecol, eval_, out);
}

// Round 9
// 213.655 us; speedup vs baseline: 1.6546x; 1.0405x over previous
//
#include <hip/hip_runtime.h>
#include <hip/hip_bf16.h>

#define BB 16
#define NN 1024
#define CS 256
#define CX 64
#define CC 320
#define PH 64
#define GH 128
#define ELLW 64
#define MTILE 128   // edges per block (2 mtiles per wave)

typedef __hip_bfloat16 bf16;
typedef __attribute__((ext_vector_type(8))) __bf16 bfrag;   // 8 bf16 = 4 VGPRs
typedef __attribute__((ext_vector_type(4))) float v4f;

// ---------------- prep: pack W1 + gc1_w (hi/lo split) into B-frag order --
// frag[ks][nt][lane][j] = w[k][n], k=ks*32+(lane>>4)*8+j, n=nt*16+(lane&15)
__global__ __launch_bounds__(256) void k_prep(
    const float* __restrict__ w1, const float* __restrict__ gc1w,
    __bf16* __restrict__ whi, __bf16* __restrict__ wlo,
    __bf16* __restrict__ gwhi, __bf16* __restrict__ gwlo,
    int* __restrict__ cnt, float* __restrict__ Ssum, float* __restrict__ S2sum)
{
    int idx = blockIdx.x * 256 + threadIdx.x;
    if (idx < 10 * 4 * 64 * 8) {          // W1: PH=64 -> 4 ntiles
        int j    = idx & 7;
        int lane = (idx >> 3) & 63;
        int nt   = (idx >> 9) & 3;
        int ks   = idx >> 11;
        int k = ks * 32 + (lane >> 4) * 8 + j;
        int n = nt * 16 + (lane & 15);
        float w = w1[k * PH + n];
        __bf16 h = (__bf16)w;
        whi[idx] = h;
        wlo[idx] = (__bf16)(w - (float)h);
    }
    if (idx < 10 * 8 * 64 * 8) {          // gc1_w: GH=128 -> 8 ntiles
        int j    = idx & 7;
        int lane = (idx >> 3) & 63;
        int nt   = (idx >> 9) & 7;
        int ks   = idx >> 12;
        int k = ks * 32 + (lane >> 4) * 8 + j;
        int n = nt * 16 + (lane & 15);
        float w = gc1w[k * GH + n];
        __bf16 h = (__bf16)w;
        gwhi[idx] = h;
        gwlo[idx] = (__bf16)(w - (float)h);
    }
    if (idx < BB * NN) cnt[idx] = 0;
    if (idx < BB * PH) { Ssum[idx] = 0.f; S2sum[idx] = 0.f; }
}

// ---------------- transpose: [B,C,N] -> featT [B,N,C] f32 ----------------
__global__ __launch_bounds__(256) void k_transpose(
    const float* __restrict__ search, const float* __restrict__ xcorr,
    float* __restrict__ featT)
{
    __shared__ float tile[32][33];
    int blk = blockIdx.x;
    int b   = blk % BB;
    int rem = blk / BB;       // 0..319
    int ct  = rem >> 5;       // 10 channel tiles
    int ntl = rem & 31;       // 32 node tiles
    int tid = threadIdx.x;
    int cl = tid >> 5, nl = tid & 31;
    const float* sb = search + (size_t)b * CS * NN;
    const float* xb = xcorr + (size_t)b * CX * NN;
    #pragma unroll
    for (int f = 0; f < 4; ++f) {
        int c = ct * 32 + cl + f * 8;
        int n = ntl * 32 + nl;
        float v = (c < CS) ? sb[(size_t)c * NN + n] : xb[(size_t)(c - CS) * NN + n];
        tile[cl + f * 8][nl] = v;
    }
    __syncthreads();
    #pragma unroll
    for (int f = 0; f < 4; ++f) {
        int nr = cl + f * 8;
        int cc = nl;
        featT[((size_t)b * NN + ntl * 32 + nr) * CC + ct * 32 + cc] = tile[cc][nr];
    }
}

// ------ stage 1: h = |f_i - f_j| @ W1 (split-bf16 MFMA) -> f32 [B,E,64]
//   Full 80 KB B-fragment set (whi||wlo) staged once per block in LDS;
//   BN-stat LDS arrays ALIASED into Wsh after the K-loop (exactly 80 KB
//   declared -> 2 blocks/CU). A-gather 2-deep prefetch from XCD-local featT.
__global__ __launch_bounds__(256, 2) void k_edge_gemm(
    const float* __restrict__ featT, const int* __restrict__ pairs,
    const uint4* __restrict__ wglob,   // whi||wlo contiguous, 81920 B
    const float* __restrict__ b1, float* __restrict__ hstore,
    float* __restrict__ Ssum, float* __restrict__ S2sum, int E)
{
    __shared__ ushort Wsh[40960];      // 80 KB: [0:20480) hi, [20480:40960) lo
    float* sS  = (float*)Wsh;          // valid only AFTER post-K-loop barrier
    float* sS2 = ((float*)Wsh) + PH;

    int t = threadIdx.x;
    {   // cooperative W load: 5120 uint4, 20 per thread
        uint4* dst = (uint4*)Wsh;
        #pragma unroll
        for (int k = 0; k < 20; ++k)
            dst[t + k * 256] = wglob[t + k * 256];
    }

    int b  = blockIdx.x % BB;
    int e0 = (blockIdx.x / BB) * MTILE;
    int wave = t >> 6, lane = t & 63;
    int q = lane >> 4, r = lane & 15;

    const float* pI[2];
    const float* pJ[2];
    #pragma unroll
    for (int mt = 0; mt < 2; ++mt) {
        int e = e0 + (wave * 2 + mt) * 16 + r;
        int ec = e < E ? e : E - 1;
        int i = pairs[((size_t)b * E + ec) * 2 + 0];
        int j = pairs[((size_t)b * E + ec) * 2 + 1];
        pI[mt] = featT + ((size_t)b * NN + i) * CC + q * 8;
        pJ[mt] = featT + ((size_t)b * NN + j) * CC + q * 8;
    }

    v4f acc[2][4];
    #pragma unroll
    for (int mt = 0; mt < 2; ++mt)
        #pragma unroll
        for (int nt = 0; nt < 4; ++nt) acc[mt][nt] = (v4f)0.f;

    float fi[3][2][8], fj[3][2][8];
    auto LOAD = [&](int ks, int buf) {
        #pragma unroll
        for (int mt = 0; mt < 2; ++mt) {
            const float4* a = (const float4*)(pI[mt] + ks * 32);
            const float4* c = (const float4*)(pJ[mt] + ks * 32);
            *(float4*)&fi[buf][mt][0] = a[0];
            *(float4*)&fi[buf][mt][4] = a[1];
            *(float4*)&fj[buf][mt][0] = c[0];
            *(float4*)&fj[buf][mt][4] = c[1];
        }
    };

    LOAD(0, 0);
    LOAD(1, 1);
    __syncthreads();   // Wsh ready

    const bfrag* WH = (const bfrag*)Wsh;
    const bfrag* WL = (const bfrag*)(Wsh + 20480);   // byte offset 40960

    #pragma unroll
    for (int ks = 0; ks < 10; ++ks) {
        int cur = ks % 3;
        if (ks + 2 < 10) LOAD(ks + 2, (ks + 2) % 3);

        bfrag ah[2], al[2];
        #pragma unroll
        for (int mt = 0; mt < 2; ++mt)
            #pragma unroll
            for (int kk = 0; kk < 8; ++kk) {
                float d = fabsf(fi[cur][mt][kk] - fj[cur][mt][kk]);
                __bf16 h = (__bf16)d;
                ah[mt][kk] = h;
                al[mt][kk] = (__bf16)(d - (float)h);
            }

        #pragma unroll
        for (int nt = 0; nt < 4; ++nt) {
            bfrag bh = WH[((ks * 4 + nt) << 6) + lane];   // ds_read_b128
            bfrag bl = WL[((ks * 4 + nt) << 6) + lane];
            #pragma unroll
            for (int mt = 0; mt < 2; ++mt) {
                acc[mt][nt] = __builtin_amdgcn_mfma_f32_16x16x32_bf16(
                    ah[mt], bh, acc[mt][nt], 0, 0, 0);
                acc[mt][nt] = __builtin_amdgcn_mfma_f32_16x16x32_bf16(
                    ah[mt], bl, acc[mt][nt], 0, 0, 0);
                acc[mt][nt] = __builtin_amdgcn_mfma_f32_16x16x32_bf16(
                    al[mt], bh, acc[mt][nt], 0, 0, 0);
            }
        }
    }

    // epilogue: bias + store f32 h[b][e][64]; BN partials in registers
    float b1v[4];
    #pragma unroll
    for (int nt = 0; nt < 4; ++nt) b1v[nt] = b1[nt * 16 + r];

    float ps[4], ps2[4];
    #pragma unroll
    for (int nt = 0; nt < 4; ++nt) { ps[nt] = 0.f; ps2[nt] = 0.f; }

    #pragma unroll
    for (int mt = 0; mt < 2; ++mt) {
        #pragma unroll
        for (int reg = 0; reg < 4; ++reg) {
            int e = e0 + (wave * 2 + mt) * 16 + q * 4 + reg;
            if (e < E) {
                float* hp = hstore + ((size_t)b * E + e) * PH + r;
                #pragma unroll
                for (int nt = 0; nt < 4; ++nt) {
                    float v = acc[mt][nt][reg] + b1v[nt];
                    hp[nt * 16] = v;
                    ps[nt] += v;
                    ps2[nt] = fmaf(v, v, ps2[nt]);
                }
            }
        }
    }

    // reuse Wsh for BN stats now that all waves are done with B-fragments
    __syncthreads();
    if (t < PH) { sS[t] = 0.f; sS2[t] = 0.f; }
    __syncthreads();
    #pragma unroll
    for (int nt = 0; nt < 4; ++nt) {
        atomicAdd(&sS[nt * 16 + r],  ps[nt]);
        atomicAdd(&sS2[nt * 16 + r], ps2[nt]);
    }
    __syncthreads();
    if (t < PH) {
        atomicAdd(&Ssum[b * PH + t],  sS[t]);
        atomicAdd(&S2sum[b * PH + t], sS2[t]);
    }
}

// -- stage 3: BN-final (in-block) + edge value + ELL scatter --------------
__global__ __launch_bounds__(256) void k_edge_val(
    const float* __restrict__ hstore, const float* __restrict__ Ssum,
    const float* __restrict__ S2sum, const float* __restrict__ gamma,
    const float* __restrict__ beta, const float* __restrict__ w2,
    const float* __restrict__ b2, const int* __restrict__ pairs,
    int* __restrict__ cnt, int* __restrict__ ecol, float* __restrict__ eval_,
    int E)
{
    __shared__ float ca[PH], cb[PH];
    int b = blockIdx.x % BB;
    int e = (blockIdx.x / BB) * 256 + threadIdx.x;
    if (threadIdx.x < PH) {
        int l = threadIdx.x;
        float mu = Ssum[b * PH + l] / E;
        float var = S2sum[b * PH + l] / E - mu * mu;
        float A = rsqrtf(var + 1e-5f) * gamma[l];
        ca[l] = A;
        cb[l] = beta[l] - mu * A;
    }
    __syncthreads();
    if (e >= E) return;
    const float4* hp = (const float4*)(hstore + ((size_t)b * E + e) * PH);
    float acc = 0.f;
    #pragma unroll
    for (int l4 = 0; l4 < 16; ++l4) {
        float4 v = hp[l4];
        float vv[4] = {v.x, v.y, v.z, v.w};
        #pragma unroll
        for (int c = 0; c < 4; ++c) {
            int l = l4 * 4 + c;
            float x = fmaf(vv[c], ca[l], cb[l]);
            x = x > 0.f ? x : 0.f;
            acc = fmaf(x, w2[l], acc);
        }
    }
    float edge = 1.f / (1.f + __expf(-(acc + b2[0])));
    const int* cp = pairs + ((size_t)b * E + e) * 2;
    int i = cp[0], j = cp[1];
    int row = b * NN + i;
    int slot = atomicAdd(&cnt[row], 1);
    if (slot < ELLW) {
        ecol[row * ELLW + slot]  = j;
        eval_[row * ELLW + slot] = edge;
    }
}

// ------ stage 4: g1 = featT @ gc1_w  (split-bf16 MFMA)
//   16 nodes/block, wave w owns ntiles {2w,2w+1} -> 1024 blocks, light waves.
__global__ __launch_bounds__(256) void k_gc1(
    const float* __restrict__ featT, const __bf16* __restrict__ gwhi,
    const __bf16* __restrict__ gwlo, float* __restrict__ g1)
{
    int b = blockIdx.x % BB;
    int m0 = b * NN + (blockIdx.x / BB) * 16;
    int t = threadIdx.x, wave = t >> 6, lane = t & 63;
    int q = lane >> 4, r = lane & 15;
    int nt0 = wave * 2;
    const float* fp = featT + (size_t)(m0 + r) * CC + q * 8;
    const bfrag* wh = (const bfrag*)gwhi;
    const bfrag* wl = (const bfrag*)gwlo;

    v4f acc[2];
    acc[0] = (v4f)0.f; acc[1] = (v4f)0.f;

    float fa[2][8];
    auto LOADA = [&](int ks, int buf) {
        const float4* p = (const float4*)(fp + ks * 32);
        *(float4*)&fa[buf][0] = p[0];
        *(float4*)&fa[buf][4] = p[1];
    };

    LOADA(0, 0);
    #pragma unroll
    for (int ks = 0; ks < 10; ++ks) {
        int cur = ks & 1;
        if (ks < 9) LOADA(ks + 1, cur ^ 1);
        bfrag ah, al;
        #pragma unroll
        for (int kk = 0; kk < 8; ++kk) {
            float d = fa[cur][kk];
            __bf16 h = (__bf16)d;
            ah[kk] = h;
            al[kk] = (__bf16)(d - (float)h);
        }
        #pragma unroll
        for (int dnt = 0; dnt < 2; ++dnt) {
            int nt = nt0 + dnt;
            bfrag bh = wh[((ks * 8 + nt) << 6) + lane];
            bfrag bl = wl[((ks * 8 + nt) << 6) + lane];
            acc[dnt] = __builtin_amdgcn_mfma_f32_16x16x32_bf16(ah, bh, acc[dnt], 0, 0, 0);
            acc[dnt] = __builtin_amdgcn_mfma_f32_16x16x32_bf16(ah, bl, acc[dnt], 0, 0, 0);
            acc[dnt] = __builtin_amdgcn_mfma_f32_16x16x32_bf16(al, bh, acc[dnt], 0, 0, 0);
        }
    }
    #pragma unroll
    for (int dnt = 0; dnt < 2; ++dnt) {
        #pragma unroll
        for (int reg = 0; reg < 4; ++reg) {
            int m = m0 + q * 4 + reg;
            g1[(size_t)m * GH + (nt0 + dnt) * 16 + r] = acc[dnt][reg];
        }
    }
}

// ------- stage 5: h1 = leaky(adj @ g1); g2 = h1 @ gc2_w (1 node/block) ---
__global__ __launch_bounds__(128) void k_spmm1(
    const float* __restrict__ g1, const int* __restrict__ cnt,
    const int* __restrict__ ecol, const float* __restrict__ eval_,
    const float* __restrict__ w2g, float* __restrict__ g2)
{
    __shared__ float tmp[2];
    int tid = threadIdx.x;
    int b = blockIdx.x % BB;
    int node = b * NN + blockIdx.x / BB;
    float wv = w2g[tid];
    int c = cnt[node];
    const int* ec = ecol + (size_t)node * ELLW;
    const float* ev = eval_ + (size_t)node * ELLW;
    float acc = 0.f;
    int s = 0;
    for (; s + 4 <= c; s += 4) {
        int j0 = ec[s], j1 = ec[s + 1], j2 = ec[s + 2], j3 = ec[s + 3];
        float v0 = ev[s], v1 = ev[s + 1], v2 = ev[s + 2], v3 = ev[s + 3];
        float a0 = g1[((size_t)b * NN + j0) * GH + tid];
        float a1 = g1[((size_t)b * NN + j1) * GH + tid];
        float a2 = g1[((size_t)b * NN + j2) * GH + tid];
        float a3 = g1[((size_t)b * NN + j3) * GH + tid];
        acc = fmaf(v0, a0, acc); acc = fmaf(v1, a1, acc);
        acc = fmaf(v2, a2, acc); acc = fmaf(v3, a3, acc);
    }
    for (; s < c; ++s) {
        int j = ec[s];
        acc = fmaf(ev[s], g1[((size_t)b * NN + j) * GH + tid], acc);
    }
    float h1 = acc > 0.f ? acc : 0.2f * acc;
    float p = h1 * wv;
    #pragma unroll
    for (int off = 32; off >= 1; off >>= 1) p += __shfl_down(p, off, 64);
    if ((tid & 63) == 0) tmp[tid >> 6] = p;
    __syncthreads();
    if (tid == 0) g2[node] = tmp[0] + tmp[1];
}

// ------------- stage 6: out = sigmoid(adj @ g2) (1 wave/node, lane=slot) -
__global__ __launch_bounds__(64) void k_spmm2(
    const float* __restrict__ g2, const int* __restrict__ cnt,
    const int* __restrict__ ecol, const float* __restrict__ eval_,
    float* __restrict__ out)
{
    int b = blockIdx.x % BB;
    int node = b * NN + blockIdx.x / BB;
    int lane = threadIdx.x;
    int c = cnt[node];
    float p = 0.f;
    if (lane < c) {
        int j = ecol[(size_t)node * ELLW + lane];
        p = eval_[(size_t)node * ELLW + lane] * g2[b * NN + j];
    }
    #pragma unroll
    for (int off = 32; off >= 1; off >>= 1) p += __shfl_down(p, off, 64);
    if (lane == 0) out[node] = 1.f / (1.f + __expf(-p));
}

extern "C" void kernel_launch(void* const* d_in, const int* in_sizes, int n_in,
                              void* d_out, int out_size, void* d_ws, size_t ws_size,
                              hipStream_t stream)
{
    const float* search = (const float*)d_in[0];
    const float* xcorr  = (const float*)d_in[1];
    const int*   pairs  = (const int*)d_in[2];
    const float* w1     = (const float*)d_in[3];
    const float* b1     = (const float*)d_in[4];
    const float* gamma  = (const float*)d_in[5];
    const float* beta   = (const float*)d_in[6];
    const float* w2     = (const float*)d_in[7];
    const float* b2     = (const float*)d_in[8];
    const float* gc1w   = (const float*)d_in[9];
    const float* gc2w   = (const float*)d_in[10];
    float* out = (float*)d_out;

    int E = in_sizes[2] / (BB * 2);      // 10068
    int nb  = (E + 255) / 256;           // 40
    int nb2 = (E + MTILE - 1) / MTILE;   // 79

    char* ws = (char*)d_ws;
    size_t off = 0;
    auto alloc = [&](size_t bytes) {
        size_t o = off;
        off += (bytes + 255) & ~(size_t)255;
        return o;
    };
    __bf16* whi   = (__bf16*)(ws + alloc(10 * 4 * 64 * 8 * 2));   // 40960 B
    __bf16* wlo   = (__bf16*)(ws + alloc(10 * 4 * 64 * 8 * 2));   // contiguous after whi
    __bf16* gwhi  = (__bf16*)(ws + alloc(10 * 8 * 64 * 8 * 2));
    __bf16* gwlo  = (__bf16*)(ws + alloc(10 * 8 * 64 * 8 * 2));
    float* featT  = (float*)(ws + alloc((size_t)BB * NN * CC * 4));
    float* hstore = (float*)(ws + alloc((size_t)BB * E * PH * 4));
    float* Ssum   = (float*)(ws + alloc(BB * PH * 4));
    float* S2sum  = (float*)(ws + alloc(BB * PH * 4));
    int*   cnt    = (int*)(ws + alloc(BB * NN * 4));
    int*   ecol   = (int*)(ws + alloc((size_t)BB * NN * ELLW * 4));
    float* eval_  = (float*)(ws + alloc((size_t)BB * NN * ELLW * 4));
    float* g1     = (float*)(ws + alloc((size_t)BB * NN * GH * 4));
    float* g2     = (float*)(ws + alloc(BB * NN * 4));
    (void)ws_size; (void)n_in; (void)out_size;

    k_prep<<<dim3(160), dim3(256), 0, stream>>>(w1, gc1w, whi, wlo, gwhi, gwlo,
                                                cnt, Ssum, S2sum);
    k_transpose<<<dim3(BB * 320), dim3(256), 0, stream>>>(search, xcorr, featT);
    k_edge_gemm<<<dim3(BB * nb2), dim3(256), 0, stream>>>(featT, pairs,
                                                          (const uint4*)whi,
                                                          b1, hstore, Ssum, S2sum, E);
    k_edge_val<<<dim3(BB * nb), dim3(256), 0, stream>>>(hstore, Ssum, S2sum,
                                                        gamma, beta, w2, b2,
                                                        pairs, cnt, ecol, eval_, E);
    k_gc1<<<dim3(BB * (NN / 16)), dim3(256), 0, stream>>>(featT, gwhi, gwlo, g1);
    k_spmm1<<<dim3(BB * NN), dim3(128), 0, stream>>>(g1, cnt, ecol, eval_, gc2w, g2);
    k_spmm2<<<dim3(BB * NN), dim3(64), 0, stream>>>(g2, cnt, ecol, eval_, out);
}